// Round 2
// baseline (480.938 us; speedup 1.0000x reference)
//
#include <hip/hip_runtime.h>

#define N_NODES 100000
#define N_EDGES 600000
#define N_GRAPHS 512

// ---------------------------------------------------------------- degree
__global__ void k_init_cnt(int* cnt) {
    int i = blockIdx.x * 256 + threadIdx.x;
    if (i < N_NODES) cnt[i] = 1;             // self-loop contributes 1 to deg
}

__global__ void k_hist(const int* __restrict__ dst, int* cnt) {
    int e = blockIdx.x * 256 + threadIdx.x;
    if (e < N_EDGES) atomicAdd(&cnt[dst[e]], 1);
}

__global__ void k_dis(const int* __restrict__ cnt, float* __restrict__ dis) {
    int i = blockIdx.x * 256 + threadIdx.x;
    if (i < N_NODES) dis[i] = 1.0f / sqrtf((float)cnt[i]);  // deg >= 1 always
}

// ---------------------------------------------------------------- scan (exclusive, over cnt[i]-1)
__global__ void k_scan1(const int* __restrict__ cnt, int* __restrict__ part) {
    __shared__ int s[256];
    int t = threadIdx.x;
    int i = blockIdx.x * 256 + t;
    int v = (i < N_NODES) ? cnt[i] - 1 : 0;
    s[t] = v; __syncthreads();
    for (int off = 128; off > 0; off >>= 1) {
        if (t < off) s[t] += s[t + off];
        __syncthreads();
    }
    if (t == 0) part[blockIdx.x] = s[0];
}

__global__ void k_scan2(int* __restrict__ part, int* __restrict__ row_ptr, int nb) {
    __shared__ int s[512];
    int t = threadIdx.x;
    int v = (t < nb) ? part[t] : 0;
    int orig = v;
    s[t] = v; __syncthreads();
    for (int off = 1; off < 512; off <<= 1) {
        int u = (t >= off) ? s[t - off] : 0;
        __syncthreads();
        s[t] += u;
        __syncthreads();
    }
    if (t < nb) part[t] = s[t] - orig;       // exclusive
    if (t == 0) row_ptr[N_NODES] = N_EDGES;
}

__global__ void k_scan3(const int* __restrict__ cnt, const int* __restrict__ part,
                        int* __restrict__ row_ptr, int* __restrict__ cursor) {
    __shared__ int s[256];
    int t = threadIdx.x;
    int i = blockIdx.x * 256 + t;
    int v = (i < N_NODES) ? cnt[i] - 1 : 0;
    s[t] = v; __syncthreads();
    for (int off = 1; off < 256; off <<= 1) {
        int u = (t >= off) ? s[t - off] : 0;
        __syncthreads();
        s[t] += u;
        __syncthreads();
    }
    int ex = s[t] - v + part[blockIdx.x];
    if (i < N_NODES) { row_ptr[i] = ex; cursor[i] = ex; }
}

// ---------------------------------------------------------------- CSR scatter
__global__ void k_scatter(const int* __restrict__ src, const int* __restrict__ dst,
                          const float* __restrict__ dis, int* __restrict__ cursor,
                          int* __restrict__ csr_src, float* __restrict__ csr_norm) {
    int e = blockIdx.x * 256 + threadIdx.x;
    if (e >= N_EDGES) return;
    int s = src[e], d = dst[e];
    int pos = atomicAdd(&cursor[d], 1);
    csr_src[pos] = s;
    csr_norm[pos] = dis[s] * dis[d];
}

// ---------------------------------------------------------------- aggregation F=3 (thread per node)
__global__ void k_agg_f3(const float* __restrict__ x, const float* __restrict__ dis,
                         const int* __restrict__ row_ptr, const int* __restrict__ csr_src,
                         const float* __restrict__ csr_norm, float* __restrict__ out) {
    int i = blockIdx.x * 256 + threadIdx.x;
    if (i >= N_NODES) return;
    float d = dis[i], s2 = d * d;
    float a0 = x[i * 3 + 0] * s2;
    float a1 = x[i * 3 + 1] * s2;
    float a2 = x[i * 3 + 2] * s2;
    int beg = row_ptr[i], end = row_ptr[i + 1];
    for (int e = beg; e < end; ++e) {
        int s = csr_src[e];
        float n = csr_norm[e];
        a0 += x[s * 3 + 0] * n;
        a1 += x[s * 3 + 1] * n;
        a2 += x[s * 3 + 2] * n;
    }
    out[i * 3 + 0] = a0; out[i * 3 + 1] = a1; out[i * 3 + 2] = a2;
}

// ---------------------------------------------------------------- GEMM1: [N,3]@[3,128]+b, relu
__global__ __launch_bounds__(256) void k_gemm1(const float* __restrict__ a,
                                               const float* __restrict__ W,
                                               const float* __restrict__ b,
                                               float* __restrict__ out) {
    __shared__ float Ws[384];
    __shared__ float bs[128];
    int tid = threadIdx.x;
    for (int i = tid; i < 384; i += 256) Ws[i] = W[i];   // FIX: 384 > blockDim, stride the load
    if (tid < 128) bs[tid] = b[tid];
    __syncthreads();
    int node = blockIdx.x * 8 + (tid >> 5);
    int f4 = tid & 31;
    if (node >= N_NODES) return;
    float a0 = a[node * 3 + 0], a1 = a[node * 3 + 1], a2 = a[node * 3 + 2];
    float4 o;
    float* op = (float*)&o;
    #pragma unroll
    for (int j = 0; j < 4; ++j) {
        int f = f4 * 4 + j;
        float v = bs[f] + a0 * Ws[f] + a1 * Ws[128 + f] + a2 * Ws[256 + f];
        op[j] = fmaxf(v, 0.0f);
    }
    *(float4*)(out + (size_t)node * 128 + f4 * 4) = o;
}

// ---------------------------------------------------------------- aggregation F=128 (wave per node)
__global__ __launch_bounds__(256) void k_agg128(const float* __restrict__ h,
                                                const float* __restrict__ dis,
                                                const int* __restrict__ row_ptr,
                                                const int* __restrict__ csr_src,
                                                const float* __restrict__ csr_norm,
                                                float* __restrict__ out) {
    int wid = (blockIdx.x * 256 + threadIdx.x) >> 6;
    int lane = threadIdx.x & 63;
    if (wid >= N_NODES) return;
    int beg = row_ptr[wid], end = row_ptr[wid + 1];
    float d = dis[wid], s2 = d * d;
    const float* hp = h + (size_t)wid * 128;
    float a0 = hp[lane] * s2;
    float a1 = hp[64 + lane] * s2;
    for (int e = beg; e < end; ++e) {
        int s = csr_src[e];
        float n = csr_norm[e];
        const float* p = h + (size_t)s * 128;
        a0 += p[lane] * n;
        a1 += p[64 + lane] * n;
    }
    out[(size_t)wid * 128 + lane] = a0;
    out[(size_t)wid * 128 + 64 + lane] = a1;
}

// ---------------------------------------------------------------- aggregation F=64 + bias + relu
__global__ __launch_bounds__(256) void k_agg64(const float* __restrict__ h,
                                               const float* __restrict__ dis,
                                               const int* __restrict__ row_ptr,
                                               const int* __restrict__ csr_src,
                                               const float* __restrict__ csr_norm,
                                               const float* __restrict__ bias,
                                               float* __restrict__ out) {
    int wid = (blockIdx.x * 256 + threadIdx.x) >> 6;
    int lane = threadIdx.x & 63;
    if (wid >= N_NODES) return;
    int beg = row_ptr[wid], end = row_ptr[wid + 1];
    float d = dis[wid], s2 = d * d;
    float a0 = h[(size_t)wid * 64 + lane] * s2;
    for (int e = beg; e < end; ++e) {
        int s = csr_src[e];
        float n = csr_norm[e];
        a0 += h[(size_t)s * 64 + lane] * n;
    }
    out[(size_t)wid * 64 + lane] = fmaxf(a0 + bias[lane], 0.0f);
}

// ---------------------------------------------------------------- fp32 GEMM: [N,128]@[128,BN]
// BM=128, BK=32, 256 threads as 16x16, thread tile 8 x (BN/16).
template <int BN, bool BIAS_RELU>
__global__ __launch_bounds__(256) void k_gemm(const float* __restrict__ A,
                                              const float* __restrict__ W,
                                              const float* __restrict__ bias,
                                              float* __restrict__ C) {
    constexpr int BM = 128, BK = 32, K = 128;
    constexpr int TN = (BN == 128) ? 8 : 4;
    constexpr int AP = BM + 4;                   // padded A row in LDS
    __shared__ float Asl[BK * AP];
    __shared__ float Wsl[BK * BN];
    int tid = threadIdx.x;
    int tx = tid & 15, ty = tid >> 4;
    int bm = blockIdx.x * BM;
    float acc[8][TN];
    #pragma unroll
    for (int i = 0; i < 8; ++i)
        #pragma unroll
        for (int j = 0; j < TN; ++j) acc[i][j] = 0.0f;

    for (int kt = 0; kt < K / BK; ++kt) {
        // stage A tile (BM x BK), transposed into LDS as [k][m]
        #pragma unroll
        for (int i = 0; i < 4; ++i) {
            int id = tid + i * 256;              // 1024 float4 slots
            int row = id >> 3, c4 = id & 7;
            float4 v = make_float4(0.f, 0.f, 0.f, 0.f);
            int gr = bm + row;
            if (gr < N_NODES) v = *(const float4*)(A + (size_t)gr * K + kt * BK + c4 * 4);
            int kk = c4 * 4;
            Asl[(kk + 0) * AP + row] = v.x;
            Asl[(kk + 1) * AP + row] = v.y;
            Asl[(kk + 2) * AP + row] = v.z;
            Asl[(kk + 3) * AP + row] = v.w;
        }
        // stage W tile (BK x BN) direct
        #pragma unroll
        for (int i = 0; i < BK * BN / 4 / 256; ++i) {
            int id = tid + i * 256;
            int row = id / (BN / 4), c4 = id % (BN / 4);
            *(float4*)(Wsl + row * BN + c4 * 4) =
                *(const float4*)(W + (size_t)(kt * BK + row) * BN + c4 * 4);
        }
        __syncthreads();
        #pragma unroll
        for (int k = 0; k < BK; ++k) {
            float4 a0 = *(const float4*)(Asl + k * AP + ty * 8);
            float4 a1 = *(const float4*)(Asl + k * AP + ty * 8 + 4);
            float av[8] = {a0.x, a0.y, a0.z, a0.w, a1.x, a1.y, a1.z, a1.w};
            float bv[TN];
            float4 b0 = *(const float4*)(Wsl + k * BN + tx * 4);
            bv[0] = b0.x; bv[1] = b0.y; bv[2] = b0.z; bv[3] = b0.w;
            if constexpr (BN == 128) {
                float4 b1 = *(const float4*)(Wsl + k * BN + 64 + tx * 4);
                bv[4] = b1.x; bv[5] = b1.y; bv[6] = b1.z; bv[7] = b1.w;
            }
            #pragma unroll
            for (int i = 0; i < 8; ++i)
                #pragma unroll
                for (int j = 0; j < TN; ++j) acc[i][j] += av[i] * bv[j];
        }
        __syncthreads();
    }
    // epilogue
    #pragma unroll
    for (int i = 0; i < 8; ++i) {
        int gr = bm + ty * 8 + i;
        if (gr >= N_NODES) continue;
        float4 o0;
        float* o0p = (float*)&o0;
        #pragma unroll
        for (int j = 0; j < 4; ++j) {
            float v = acc[i][j];
            if constexpr (BIAS_RELU) v = fmaxf(v + bias[tx * 4 + j], 0.0f);
            o0p[j] = v;
        }
        *(float4*)(C + (size_t)gr * BN + tx * 4) = o0;
        if constexpr (BN == 128) {
            float4 o1;
            float* o1p = (float*)&o1;
            #pragma unroll
            for (int j = 0; j < 4; ++j) {
                float v = acc[i][4 + j];
                if constexpr (BIAS_RELU) v = fmaxf(v + bias[64 + tx * 4 + j], 0.0f);
                o1p[j] = v;
            }
            *(float4*)(C + (size_t)gr * BN + 64 + tx * 4) = o1;
        }
    }
}

// ---------------------------------------------------------------- pool + head (wave per graph)
__global__ __launch_bounds__(64) void k_pool(const float* __restrict__ h,
                                             const int* __restrict__ batch,
                                             const float* __restrict__ Wl,
                                             const float* __restrict__ bl,
                                             float* __restrict__ out) {
    int g = blockIdx.x;
    int lane = threadIdx.x;
    // lower_bound(batch, g) and lower_bound(batch, g+1) — batch is sorted
    int lo = 0, hi = N_NODES;
    while (lo < hi) { int mid = (lo + hi) >> 1; if (batch[mid] < g) lo = mid + 1; else hi = mid; }
    int lo2 = lo, hi2 = N_NODES;
    while (lo2 < hi2) { int mid = (lo2 + hi2) >> 1; if (batch[mid] < g + 1) lo2 = mid + 1; else hi2 = mid; }
    float acc = 0.0f;
    for (int n = lo; n < lo2; ++n) acc += h[(size_t)n * 64 + lane];
    float r = acc * Wl[lane];
    #pragma unroll
    for (int off = 32; off > 0; off >>= 1) r += __shfl_down(r, off, 64);
    if (lane == 0) out[g] = r / fmaxf((float)(lo2 - lo), 1.0f) + bl[0];
}

// ---------------------------------------------------------------- launcher
extern "C" void kernel_launch(void* const* d_in, const int* in_sizes, int n_in,
                              void* d_out, int out_size, void* d_ws, size_t ws_size,
                              hipStream_t stream) {
    const float* x     = (const float*)d_in[0];
    const int*   ei    = (const int*)d_in[1];     // [0..E) = src, [E..2E) = dst
    const int*   batch = (const int*)d_in[2];
    const float* W1 = (const float*)d_in[3];
    const float* b1 = (const float*)d_in[4];
    const float* W2 = (const float*)d_in[5];
    const float* b2 = (const float*)d_in[6];
    const float* W3 = (const float*)d_in[7];
    const float* b3 = (const float*)d_in[8];
    const float* Wl = (const float*)d_in[9];
    const float* bl = (const float*)d_in[10];
    float* out = (float*)d_out;

    const int* e_src = ei;
    const int* e_dst = ei + N_EDGES;

    // workspace carve-up (256B aligned)
    char* ws = (char*)d_ws;
    size_t off = 0;
    auto alloc = [&](size_t bytes) -> char* {
        char* p = ws + off;
        off = (off + bytes + 255) & ~(size_t)255;
        return p;
    };
    int*   cnt      = (int*)  alloc((size_t)N_NODES * 4);
    float* dis      = (float*)alloc((size_t)N_NODES * 4);
    int*   row_ptr  = (int*)  alloc((size_t)(N_NODES + 1) * 4);
    int*   cursor   = (int*)  alloc((size_t)N_NODES * 4);
    int*   part     = (int*)  alloc(1024 * 4);
    int*   csr_src  = (int*)  alloc((size_t)N_EDGES * 4);
    float* csr_norm = (float*)alloc((size_t)N_EDGES * 4);
    float* agg1     = (float*)alloc((size_t)N_NODES * 3 * 4);
    float* P        = (float*)alloc((size_t)N_NODES * 128 * 4);
    float* Q        = (float*)alloc((size_t)N_NODES * 128 * 4);

    const int NB_N = (N_NODES + 255) / 256;   // 391
    const int NB_E = (N_EDGES + 255) / 256;

    k_init_cnt<<<NB_N, 256, 0, stream>>>(cnt);
    k_hist<<<NB_E, 256, 0, stream>>>(e_dst, cnt);
    k_dis<<<NB_N, 256, 0, stream>>>(cnt, dis);
    k_scan1<<<NB_N, 256, 0, stream>>>(cnt, part);
    k_scan2<<<1, 512, 0, stream>>>(part, row_ptr, NB_N);
    k_scan3<<<NB_N, 256, 0, stream>>>(cnt, part, row_ptr, cursor);
    k_scatter<<<NB_E, 256, 0, stream>>>(e_src, e_dst, dis, cursor, csr_src, csr_norm);

    // layer 1: aggregate(F=3) -> GEMM 3->128 + b1 + relu
    k_agg_f3<<<NB_N, 256, 0, stream>>>(x, dis, row_ptr, csr_src, csr_norm, agg1);
    k_gemm1<<<(N_NODES + 7) / 8, 256, 0, stream>>>(agg1, W1, b1, P);

    // layer 2: aggregate(F=128) -> GEMM 128->128 + b2 + relu
    k_agg128<<<(N_NODES + 3) / 4, 256, 0, stream>>>(P, dis, row_ptr, csr_src, csr_norm, Q);
    k_gemm<128, true><<<(N_NODES + 127) / 128, 256, 0, stream>>>(Q, W2, b2, P);

    // layer 3: GEMM 128->64 (no bias) -> aggregate(F=64) + b3 + relu
    k_gemm<64, false><<<(N_NODES + 127) / 128, 256, 0, stream>>>(P, W3, nullptr, Q);
    k_agg64<<<(N_NODES + 3) / 4, 256, 0, stream>>>(Q, dis, row_ptr, csr_src, csr_norm, b3, P);

    // mean pool + linear head
    k_pool<<<N_GRAPHS, 64, 0, stream>>>(P, batch, Wl, bl, out);
}

// Round 3
// 371.371 us; speedup vs baseline: 1.2950x; 1.2950x over previous
//
#include <hip/hip_runtime.h>

#define N_NODES 100000
#define N_EDGES 600000
#define N_GRAPHS 512

// ---------------------------------------------------------------- degree
__global__ void k_init_cnt(int* cnt) {
    int i = blockIdx.x * 256 + threadIdx.x;
    if (i < N_NODES) cnt[i] = 1;             // self-loop contributes 1 to deg
}

__global__ void k_hist(const int* __restrict__ dst, int* cnt) {
    int e = blockIdx.x * 256 + threadIdx.x;
    if (e < N_EDGES) atomicAdd(&cnt[dst[e]], 1);
}

__global__ void k_dis(const int* __restrict__ cnt, float* __restrict__ dis) {
    int i = blockIdx.x * 256 + threadIdx.x;
    if (i < N_NODES) dis[i] = 1.0f / sqrtf((float)cnt[i]);  // deg >= 1 always
}

// ---------------------------------------------------------------- scan (exclusive, over cnt[i]-1)
__global__ void k_scan1(const int* __restrict__ cnt, int* __restrict__ part) {
    __shared__ int s[256];
    int t = threadIdx.x;
    int i = blockIdx.x * 256 + t;
    int v = (i < N_NODES) ? cnt[i] - 1 : 0;
    s[t] = v; __syncthreads();
    for (int off = 128; off > 0; off >>= 1) {
        if (t < off) s[t] += s[t + off];
        __syncthreads();
    }
    if (t == 0) part[blockIdx.x] = s[0];
}

__global__ void k_scan2(int* __restrict__ part, int* __restrict__ row_ptr, int nb) {
    __shared__ int s[512];
    int t = threadIdx.x;
    int v = (t < nb) ? part[t] : 0;
    int orig = v;
    s[t] = v; __syncthreads();
    for (int off = 1; off < 512; off <<= 1) {
        int u = (t >= off) ? s[t - off] : 0;
        __syncthreads();
        s[t] += u;
        __syncthreads();
    }
    if (t < nb) part[t] = s[t] - orig;       // exclusive
    if (t == 0) row_ptr[N_NODES] = N_EDGES;
}

__global__ void k_scan3(const int* __restrict__ cnt, const int* __restrict__ part,
                        int* __restrict__ row_ptr, int* __restrict__ cursor) {
    __shared__ int s[256];
    int t = threadIdx.x;
    int i = blockIdx.x * 256 + t;
    int v = (i < N_NODES) ? cnt[i] - 1 : 0;
    s[t] = v; __syncthreads();
    for (int off = 1; off < 256; off <<= 1) {
        int u = (t >= off) ? s[t - off] : 0;
        __syncthreads();
        s[t] += u;
        __syncthreads();
    }
    int ex = s[t] - v + part[blockIdx.x];
    if (i < N_NODES) { row_ptr[i] = ex; cursor[i] = ex; }
}

// ---------------------------------------------------------------- CSR scatter
__global__ void k_scatter(const int* __restrict__ src, const int* __restrict__ dst,
                          const float* __restrict__ dis, int* __restrict__ cursor,
                          int* __restrict__ csr_src, float* __restrict__ csr_norm) {
    int e = blockIdx.x * 256 + threadIdx.x;
    if (e >= N_EDGES) return;
    int s = src[e], d = dst[e];
    int pos = atomicAdd(&cursor[d], 1);
    csr_src[pos] = s;
    csr_norm[pos] = dis[s] * dis[d];
}

// ---------------------------------------------------------------- aggregation F=3 (thread per node)
__global__ void k_agg_f3(const float* __restrict__ x, const float* __restrict__ dis,
                         const int* __restrict__ row_ptr, const int* __restrict__ csr_src,
                         const float* __restrict__ csr_norm, float* __restrict__ out) {
    int i = blockIdx.x * 256 + threadIdx.x;
    if (i >= N_NODES) return;
    float d = dis[i], s2 = d * d;
    float a0 = x[i * 3 + 0] * s2;
    float a1 = x[i * 3 + 1] * s2;
    float a2 = x[i * 3 + 2] * s2;
    int beg = row_ptr[i], end = row_ptr[i + 1];
    int e = beg;
    for (; e + 4 <= end; e += 4) {                  // batch 4 edges: indices first,
        int s0 = csr_src[e], s1 = csr_src[e + 1];   // then 12 gathers in flight
        int sA = csr_src[e + 2], sB = csr_src[e + 3];
        float n0 = csr_norm[e], n1 = csr_norm[e + 1];
        float n2 = csr_norm[e + 2], n3 = csr_norm[e + 3];
        float x00 = x[s0 * 3], x01 = x[s0 * 3 + 1], x02 = x[s0 * 3 + 2];
        float x10 = x[s1 * 3], x11 = x[s1 * 3 + 1], x12 = x[s1 * 3 + 2];
        float x20 = x[sA * 3], x21 = x[sA * 3 + 1], x22 = x[sA * 3 + 2];
        float x30 = x[sB * 3], x31 = x[sB * 3 + 1], x32 = x[sB * 3 + 2];
        a0 = fmaf(x00, n0, a0); a1 = fmaf(x01, n0, a1); a2 = fmaf(x02, n0, a2);
        a0 = fmaf(x10, n1, a0); a1 = fmaf(x11, n1, a1); a2 = fmaf(x12, n1, a2);
        a0 = fmaf(x20, n2, a0); a1 = fmaf(x21, n2, a1); a2 = fmaf(x22, n2, a2);
        a0 = fmaf(x30, n3, a0); a1 = fmaf(x31, n3, a1); a2 = fmaf(x32, n3, a2);
    }
    for (; e < end; ++e) {
        int s = csr_src[e];
        float n = csr_norm[e];
        a0 = fmaf(x[s * 3 + 0], n, a0);
        a1 = fmaf(x[s * 3 + 1], n, a1);
        a2 = fmaf(x[s * 3 + 2], n, a2);
    }
    out[i * 3 + 0] = a0; out[i * 3 + 1] = a1; out[i * 3 + 2] = a2;
}

// ---------------------------------------------------------------- GEMM1: [N,3]@[3,128]+b, relu
__global__ __launch_bounds__(256) void k_gemm1(const float* __restrict__ a,
                                               const float* __restrict__ W,
                                               const float* __restrict__ b,
                                               float* __restrict__ out) {
    __shared__ float Ws[384];
    __shared__ float bs[128];
    int tid = threadIdx.x;
    for (int i = tid; i < 384; i += 256) Ws[i] = W[i];
    if (tid < 128) bs[tid] = b[tid];
    __syncthreads();
    int node = blockIdx.x * 8 + (tid >> 5);
    int f4 = tid & 31;
    if (node >= N_NODES) return;
    float a0 = a[node * 3 + 0], a1 = a[node * 3 + 1], a2 = a[node * 3 + 2];
    float4 o;
    float* op = (float*)&o;
    #pragma unroll
    for (int j = 0; j < 4; ++j) {
        int f = f4 * 4 + j;
        float v = bs[f] + a0 * Ws[f] + a1 * Ws[128 + f] + a2 * Ws[256 + f];
        op[j] = fmaxf(v, 0.0f);
    }
    *(float4*)(out + (size_t)node * 128 + f4 * 4) = o;
}

// ---------------------------------------------------------------- aggregation F=128 (wave per node)
__global__ __launch_bounds__(256) void k_agg128(const float* __restrict__ h,
                                                const float* __restrict__ dis,
                                                const int* __restrict__ row_ptr,
                                                const int* __restrict__ csr_src,
                                                const float* __restrict__ csr_norm,
                                                float* __restrict__ out) {
    int wid = (blockIdx.x * 256 + threadIdx.x) >> 6;
    int lane = threadIdx.x & 63;
    if (wid >= N_NODES) return;
    int beg = row_ptr[wid], end = row_ptr[wid + 1];
    float d = dis[wid], s2 = d * d;
    const float* hp = h + (size_t)wid * 128;
    float a0 = hp[lane] * s2;
    float a1 = hp[64 + lane] * s2;
    int e = beg;
    for (; e + 4 <= end; e += 4) {                  // 4 indices, then 8 gathers in flight
        int s0 = csr_src[e],     s1 = csr_src[e + 1];
        int sA = csr_src[e + 2], sB = csr_src[e + 3];
        float n0 = csr_norm[e],     n1 = csr_norm[e + 1];
        float n2 = csr_norm[e + 2], n3 = csr_norm[e + 3];
        const float* p0 = h + (size_t)s0 * 128;
        const float* p1 = h + (size_t)s1 * 128;
        const float* p2 = h + (size_t)sA * 128;
        const float* p3 = h + (size_t)sB * 128;
        float x00 = p0[lane], x01 = p0[64 + lane];
        float x10 = p1[lane], x11 = p1[64 + lane];
        float x20 = p2[lane], x21 = p2[64 + lane];
        float x30 = p3[lane], x31 = p3[64 + lane];
        a0 = fmaf(x00, n0, a0); a1 = fmaf(x01, n0, a1);
        a0 = fmaf(x10, n1, a0); a1 = fmaf(x11, n1, a1);
        a0 = fmaf(x20, n2, a0); a1 = fmaf(x21, n2, a1);
        a0 = fmaf(x30, n3, a0); a1 = fmaf(x31, n3, a1);
    }
    for (; e < end; ++e) {
        int s = csr_src[e];
        float n = csr_norm[e];
        const float* p = h + (size_t)s * 128;
        a0 = fmaf(p[lane], n, a0);
        a1 = fmaf(p[64 + lane], n, a1);
    }
    out[(size_t)wid * 128 + lane] = a0;
    out[(size_t)wid * 128 + 64 + lane] = a1;
}

// ---------------------------------------------------------------- aggregation F=64 + bias + relu + Wl dot
// h3 is never materialized: s_out[n] = relu(agg + b3) . Wl
__global__ __launch_bounds__(256) void k_agg64_dot(const float* __restrict__ h,
                                                   const float* __restrict__ dis,
                                                   const int* __restrict__ row_ptr,
                                                   const int* __restrict__ csr_src,
                                                   const float* __restrict__ csr_norm,
                                                   const float* __restrict__ bias,
                                                   const float* __restrict__ Wl,
                                                   float* __restrict__ s_out) {
    int wid = (blockIdx.x * 256 + threadIdx.x) >> 6;
    int lane = threadIdx.x & 63;
    if (wid >= N_NODES) return;
    int beg = row_ptr[wid], end = row_ptr[wid + 1];
    float d = dis[wid], s2 = d * d;
    float a0 = h[(size_t)wid * 64 + lane] * s2;
    int e = beg;
    for (; e + 4 <= end; e += 4) {
        int s0 = csr_src[e],     s1 = csr_src[e + 1];
        int sA = csr_src[e + 2], sB = csr_src[e + 3];
        float n0 = csr_norm[e],     n1 = csr_norm[e + 1];
        float n2 = csr_norm[e + 2], n3 = csr_norm[e + 3];
        float x0 = h[(size_t)s0 * 64 + lane];
        float x1 = h[(size_t)s1 * 64 + lane];
        float x2 = h[(size_t)sA * 64 + lane];
        float x3 = h[(size_t)sB * 64 + lane];
        a0 = fmaf(x0, n0, a0);
        a0 = fmaf(x1, n1, a0);
        a0 = fmaf(x2, n2, a0);
        a0 = fmaf(x3, n3, a0);
    }
    for (; e < end; ++e) {
        a0 = fmaf(h[(size_t)csr_src[e] * 64 + lane], csr_norm[e], a0);
    }
    float v = fmaxf(a0 + bias[lane], 0.0f) * Wl[lane];
    #pragma unroll
    for (int off = 32; off > 0; off >>= 1) v += __shfl_down(v, off, 64);
    if (lane == 0) s_out[wid] = v;
}

// ---------------------------------------------------------------- fp32 GEMM: [N,128]@[128,BN]
template <int BN, bool BIAS_RELU>
__global__ __launch_bounds__(256) void k_gemm(const float* __restrict__ A,
                                              const float* __restrict__ W,
                                              const float* __restrict__ bias,
                                              float* __restrict__ C) {
    constexpr int BM = 128, BK = 32, K = 128;
    constexpr int TN = (BN == 128) ? 8 : 4;
    constexpr int AP = BM + 4;                   // padded A row in LDS
    __shared__ float Asl[BK * AP];
    __shared__ float Wsl[BK * BN];
    int tid = threadIdx.x;
    int tx = tid & 15, ty = tid >> 4;
    int bm = blockIdx.x * BM;
    float acc[8][TN];
    #pragma unroll
    for (int i = 0; i < 8; ++i)
        #pragma unroll
        for (int j = 0; j < TN; ++j) acc[i][j] = 0.0f;

    for (int kt = 0; kt < K / BK; ++kt) {
        #pragma unroll
        for (int i = 0; i < 4; ++i) {
            int id = tid + i * 256;              // 1024 float4 slots
            int row = id >> 3, c4 = id & 7;
            float4 v = make_float4(0.f, 0.f, 0.f, 0.f);
            int gr = bm + row;
            if (gr < N_NODES) v = *(const float4*)(A + (size_t)gr * K + kt * BK + c4 * 4);
            int kk = c4 * 4;
            Asl[(kk + 0) * AP + row] = v.x;
            Asl[(kk + 1) * AP + row] = v.y;
            Asl[(kk + 2) * AP + row] = v.z;
            Asl[(kk + 3) * AP + row] = v.w;
        }
        #pragma unroll
        for (int i = 0; i < BK * BN / 4 / 256; ++i) {
            int id = tid + i * 256;
            int row = id / (BN / 4), c4 = id % (BN / 4);
            *(float4*)(Wsl + row * BN + c4 * 4) =
                *(const float4*)(W + (size_t)(kt * BK + row) * BN + c4 * 4);
        }
        __syncthreads();
        #pragma unroll
        for (int k = 0; k < BK; ++k) {
            float4 a0 = *(const float4*)(Asl + k * AP + ty * 8);
            float4 a1 = *(const float4*)(Asl + k * AP + ty * 8 + 4);
            float av[8] = {a0.x, a0.y, a0.z, a0.w, a1.x, a1.y, a1.z, a1.w};
            float bv[TN];
            float4 b0 = *(const float4*)(Wsl + k * BN + tx * 4);
            bv[0] = b0.x; bv[1] = b0.y; bv[2] = b0.z; bv[3] = b0.w;
            if constexpr (BN == 128) {
                float4 b1 = *(const float4*)(Wsl + k * BN + 64 + tx * 4);
                bv[4] = b1.x; bv[5] = b1.y; bv[6] = b1.z; bv[7] = b1.w;
            }
            #pragma unroll
            for (int i = 0; i < 8; ++i)
                #pragma unroll
                for (int j = 0; j < TN; ++j) acc[i][j] += av[i] * bv[j];
        }
        __syncthreads();
    }
    #pragma unroll
    for (int i = 0; i < 8; ++i) {
        int gr = bm + ty * 8 + i;
        if (gr >= N_NODES) continue;
        float4 o0;
        float* o0p = (float*)&o0;
        #pragma unroll
        for (int j = 0; j < 4; ++j) {
            float v = acc[i][j];
            if constexpr (BIAS_RELU) v = fmaxf(v + bias[tx * 4 + j], 0.0f);
            o0p[j] = v;
        }
        *(float4*)(C + (size_t)gr * BN + tx * 4) = o0;
        if constexpr (BN == 128) {
            float4 o1;
            float* o1p = (float*)&o1;
            #pragma unroll
            for (int j = 0; j < 4; ++j) {
                float v = acc[i][4 + j];
                if constexpr (BIAS_RELU) v = fmaxf(v + bias[64 + tx * 4 + j], 0.0f);
                o1p[j] = v;
            }
            *(float4*)(C + (size_t)gr * BN + 64 + tx * 4) = o1;
        }
    }
}

// ---------------------------------------------------------------- pool over per-node scalars
__global__ __launch_bounds__(256) void k_pool2(const float* __restrict__ s,
                                               const int* __restrict__ batch,
                                               const float* __restrict__ bl,
                                               float* __restrict__ out) {
    int g = blockIdx.x;
    int tid = threadIdx.x;
    int lo = 0, hi = N_NODES;
    while (lo < hi) { int m = (lo + hi) >> 1; if (batch[m] < g) lo = m + 1; else hi = m; }
    int lo2 = lo, hi2 = N_NODES;
    while (lo2 < hi2) { int m = (lo2 + hi2) >> 1; if (batch[m] < g + 1) lo2 = m + 1; else hi2 = m; }
    float acc = 0.0f;
    for (int n = lo + tid; n < lo2; n += 256) acc += s[n];
    __shared__ float sm[256];
    sm[tid] = acc; __syncthreads();
    for (int off = 128; off > 0; off >>= 1) {
        if (tid < off) sm[tid] += sm[tid + off];
        __syncthreads();
    }
    if (tid == 0) out[g] = sm[0] / fmaxf((float)(lo2 - lo), 1.0f) + bl[0];
}

// ---------------------------------------------------------------- launcher
extern "C" void kernel_launch(void* const* d_in, const int* in_sizes, int n_in,
                              void* d_out, int out_size, void* d_ws, size_t ws_size,
                              hipStream_t stream) {
    const float* x     = (const float*)d_in[0];
    const int*   ei    = (const int*)d_in[1];     // [0..E) = src, [E..2E) = dst
    const int*   batch = (const int*)d_in[2];
    const float* W1 = (const float*)d_in[3];
    const float* b1 = (const float*)d_in[4];
    const float* W2 = (const float*)d_in[5];
    const float* b2 = (const float*)d_in[6];
    const float* W3 = (const float*)d_in[7];
    const float* b3 = (const float*)d_in[8];
    const float* Wl = (const float*)d_in[9];
    const float* bl = (const float*)d_in[10];
    float* out = (float*)d_out;

    const int* e_src = ei;
    const int* e_dst = ei + N_EDGES;

    char* ws = (char*)d_ws;
    size_t off = 0;
    auto alloc = [&](size_t bytes) -> char* {
        char* p = ws + off;
        off = (off + bytes + 255) & ~(size_t)255;
        return p;
    };
    int*   cnt      = (int*)  alloc((size_t)N_NODES * 4);
    float* dis      = (float*)alloc((size_t)N_NODES * 4);
    int*   row_ptr  = (int*)  alloc((size_t)(N_NODES + 1) * 4);
    int*   cursor   = (int*)  alloc((size_t)N_NODES * 4);
    int*   part     = (int*)  alloc(1024 * 4);
    int*   csr_src  = (int*)  alloc((size_t)N_EDGES * 4);
    float* csr_norm = (float*)alloc((size_t)N_EDGES * 4);
    float* agg1     = (float*)alloc((size_t)N_NODES * 3 * 4);
    float* nscal    = (float*)alloc((size_t)N_NODES * 4);
    float* P        = (float*)alloc((size_t)N_NODES * 128 * 4);
    float* Q        = (float*)alloc((size_t)N_NODES * 128 * 4);

    const int NB_N = (N_NODES + 255) / 256;   // 391
    const int NB_E = (N_EDGES + 255) / 256;

    k_init_cnt<<<NB_N, 256, 0, stream>>>(cnt);
    k_hist<<<NB_E, 256, 0, stream>>>(e_dst, cnt);
    k_dis<<<NB_N, 256, 0, stream>>>(cnt, dis);
    k_scan1<<<NB_N, 256, 0, stream>>>(cnt, part);
    k_scan2<<<1, 512, 0, stream>>>(part, row_ptr, NB_N);
    k_scan3<<<NB_N, 256, 0, stream>>>(cnt, part, row_ptr, cursor);
    k_scatter<<<NB_E, 256, 0, stream>>>(e_src, e_dst, dis, cursor, csr_src, csr_norm);

    // layer 1: aggregate(F=3) -> GEMM 3->128 + b1 + relu
    k_agg_f3<<<NB_N, 256, 0, stream>>>(x, dis, row_ptr, csr_src, csr_norm, agg1);
    k_gemm1<<<(N_NODES + 7) / 8, 256, 0, stream>>>(agg1, W1, b1, P);

    // layer 2: aggregate(F=128) -> GEMM 128->128 + b2 + relu
    k_agg128<<<(N_NODES + 3) / 4, 256, 0, stream>>>(P, dis, row_ptr, csr_src, csr_norm, Q);
    k_gemm<128, true><<<(N_NODES + 127) / 128, 256, 0, stream>>>(Q, W2, b2, P);

    // layer 3: GEMM 128->64 (no bias) -> aggregate(F=64)+b3+relu+dot(Wl) fused
    k_gemm<64, false><<<(N_NODES + 127) / 128, 256, 0, stream>>>(P, W3, nullptr, Q);
    k_agg64_dot<<<(N_NODES + 3) / 4, 256, 0, stream>>>(Q, dis, row_ptr, csr_src, csr_norm,
                                                       b3, Wl, nscal);

    // mean pool (+ bl) over per-node scalars
    k_pool2<<<N_GRAPHS, 256, 0, stream>>>(nscal, batch, bl, out);
}

// Round 4
// 296.914 us; speedup vs baseline: 1.6198x; 1.2508x over previous
//
#include <hip/hip_runtime.h>

#define N_NODES 100000
#define N_EDGES 600000
#define N_GRAPHS 512

typedef __attribute__((ext_vector_type(8))) short short8;
typedef __attribute__((ext_vector_type(4))) float floatx4;

__device__ __forceinline__ unsigned short f2bf(float f) {   // RNE f32 -> bf16
    unsigned int u = __float_as_uint(f);
    u += 0x7FFFu + ((u >> 16) & 1u);
    return (unsigned short)(u >> 16);
}
__device__ __forceinline__ float bf_lo(unsigned int u) { return __uint_as_float(u << 16); }
__device__ __forceinline__ float bf_hi(unsigned int u) { return __uint_as_float(u & 0xFFFF0000u); }

// ---------------------------------------------------------------- degree
__global__ void k_init_cnt(int* cnt) {
    int i = blockIdx.x * 256 + threadIdx.x;
    if (i < N_NODES) cnt[i] = 1;             // self-loop contributes 1 to deg
}

__global__ void k_hist(const int* __restrict__ dst, int* cnt) {
    int e = blockIdx.x * 256 + threadIdx.x;
    if (e < N_EDGES) atomicAdd(&cnt[dst[e]], 1);
}

__global__ void k_dis(const int* __restrict__ cnt, float* __restrict__ dis) {
    int i = blockIdx.x * 256 + threadIdx.x;
    if (i < N_NODES) dis[i] = 1.0f / sqrtf((float)cnt[i]);  // deg >= 1 always
}

// ---------------------------------------------------------------- scan (exclusive, over cnt[i]-1)
__global__ void k_scan1(const int* __restrict__ cnt, int* __restrict__ part) {
    __shared__ int s[256];
    int t = threadIdx.x;
    int i = blockIdx.x * 256 + t;
    int v = (i < N_NODES) ? cnt[i] - 1 : 0;
    s[t] = v; __syncthreads();
    for (int off = 128; off > 0; off >>= 1) {
        if (t < off) s[t] += s[t + off];
        __syncthreads();
    }
    if (t == 0) part[blockIdx.x] = s[0];
}

__global__ void k_scan2(int* __restrict__ part, int* __restrict__ row_ptr, int nb) {
    __shared__ int s[512];
    int t = threadIdx.x;
    int v = (t < nb) ? part[t] : 0;
    int orig = v;
    s[t] = v; __syncthreads();
    for (int off = 1; off < 512; off <<= 1) {
        int u = (t >= off) ? s[t - off] : 0;
        __syncthreads();
        s[t] += u;
        __syncthreads();
    }
    if (t < nb) part[t] = s[t] - orig;       // exclusive
    if (t == 0) row_ptr[N_NODES] = N_EDGES;
}

__global__ void k_scan3(const int* __restrict__ cnt, const int* __restrict__ part,
                        int* __restrict__ row_ptr, int* __restrict__ cursor) {
    __shared__ int s[256];
    int t = threadIdx.x;
    int i = blockIdx.x * 256 + t;
    int v = (i < N_NODES) ? cnt[i] - 1 : 0;
    s[t] = v; __syncthreads();
    for (int off = 1; off < 256; off <<= 1) {
        int u = (t >= off) ? s[t - off] : 0;
        __syncthreads();
        s[t] += u;
        __syncthreads();
    }
    int ex = s[t] - v + part[blockIdx.x];
    if (i < N_NODES) { row_ptr[i] = ex; cursor[i] = ex; }
}

// ---------------------------------------------------------------- CSR scatter
__global__ void k_scatter(const int* __restrict__ src, const int* __restrict__ dst,
                          const float* __restrict__ dis, int* __restrict__ cursor,
                          int* __restrict__ csr_src, float* __restrict__ csr_norm) {
    int e = blockIdx.x * 256 + threadIdx.x;
    if (e >= N_EDGES) return;
    int s = src[e], d = dst[e];
    int pos = atomicAdd(&cursor[d], 1);
    csr_src[pos] = s;
    csr_norm[pos] = dis[s] * dis[d];
}

// ---------------------------------------------------------------- aggregation F=3 (thread per node)
__global__ void k_agg_f3(const float* __restrict__ x, const float* __restrict__ dis,
                         const int* __restrict__ row_ptr, const int* __restrict__ csr_src,
                         const float* __restrict__ csr_norm, float* __restrict__ out) {
    int i = blockIdx.x * 256 + threadIdx.x;
    if (i >= N_NODES) return;
    float d = dis[i], s2 = d * d;
    float a0 = x[i * 3 + 0] * s2;
    float a1 = x[i * 3 + 1] * s2;
    float a2 = x[i * 3 + 2] * s2;
    int beg = row_ptr[i], end = row_ptr[i + 1];
    int e = beg;
    for (; e + 4 <= end; e += 4) {                  // batch 4 edges: indices first,
        int s0 = csr_src[e], s1 = csr_src[e + 1];   // then 12 gathers in flight
        int sA = csr_src[e + 2], sB = csr_src[e + 3];
        float n0 = csr_norm[e], n1 = csr_norm[e + 1];
        float n2 = csr_norm[e + 2], n3 = csr_norm[e + 3];
        float x00 = x[s0 * 3], x01 = x[s0 * 3 + 1], x02 = x[s0 * 3 + 2];
        float x10 = x[s1 * 3], x11 = x[s1 * 3 + 1], x12 = x[s1 * 3 + 2];
        float x20 = x[sA * 3], x21 = x[sA * 3 + 1], x22 = x[sA * 3 + 2];
        float x30 = x[sB * 3], x31 = x[sB * 3 + 1], x32 = x[sB * 3 + 2];
        a0 = fmaf(x00, n0, a0); a1 = fmaf(x01, n0, a1); a2 = fmaf(x02, n0, a2);
        a0 = fmaf(x10, n1, a0); a1 = fmaf(x11, n1, a1); a2 = fmaf(x12, n1, a2);
        a0 = fmaf(x20, n2, a0); a1 = fmaf(x21, n2, a1); a2 = fmaf(x22, n2, a2);
        a0 = fmaf(x30, n3, a0); a1 = fmaf(x31, n3, a1); a2 = fmaf(x32, n3, a2);
    }
    for (; e < end; ++e) {
        int s = csr_src[e];
        float n = csr_norm[e];
        a0 = fmaf(x[s * 3 + 0], n, a0);
        a1 = fmaf(x[s * 3 + 1], n, a1);
        a2 = fmaf(x[s * 3 + 2], n, a2);
    }
    out[i * 3 + 0] = a0; out[i * 3 + 1] = a1; out[i * 3 + 2] = a2;
}

// ---------------------------------------------------------------- GEMM1: [N,3]@[3,128]+b, relu -> bf16
__global__ __launch_bounds__(256) void k_gemm1(const float* __restrict__ a,
                                               const float* __restrict__ W,
                                               const float* __restrict__ b,
                                               unsigned short* __restrict__ out) {
    __shared__ float Ws[384];
    __shared__ float bs[128];
    int tid = threadIdx.x;
    for (int i = tid; i < 384; i += 256) Ws[i] = W[i];
    if (tid < 128) bs[tid] = b[tid];
    __syncthreads();
    int node = blockIdx.x * 8 + (tid >> 5);
    int f4 = tid & 31;
    if (node >= N_NODES) return;
    float a0 = a[node * 3 + 0], a1 = a[node * 3 + 1], a2 = a[node * 3 + 2];
    ushort4 o;
    unsigned short* op = (unsigned short*)&o;
    #pragma unroll
    for (int j = 0; j < 4; ++j) {
        int f = f4 * 4 + j;
        float v = bs[f] + a0 * Ws[f] + a1 * Ws[128 + f] + a2 * Ws[256 + f];
        op[j] = f2bf(fmaxf(v, 0.0f));
    }
    *(ushort4*)(out + (size_t)node * 128 + f4 * 4) = o;
}

// ---------------------------------------------------------------- aggregation F=128 bf16 (wave per node)
// lane handles features 2*lane, 2*lane+1 (uint = 2 bf16)
__global__ __launch_bounds__(256) void k_agg128_bf16(const unsigned short* __restrict__ h,
                                                     const float* __restrict__ dis,
                                                     const int* __restrict__ row_ptr,
                                                     const int* __restrict__ csr_src,
                                                     const float* __restrict__ csr_norm,
                                                     unsigned short* __restrict__ out) {
    int wid = (blockIdx.x * 256 + threadIdx.x) >> 6;
    int lane = threadIdx.x & 63;
    if (wid >= N_NODES) return;
    int beg = row_ptr[wid], end = row_ptr[wid + 1];
    float d = dis[wid], s2 = d * d;
    unsigned int su = *(const unsigned int*)(h + (size_t)wid * 128 + 2 * lane);
    float a0 = bf_lo(su) * s2;
    float a1 = bf_hi(su) * s2;
    int e = beg;
    for (; e + 4 <= end; e += 4) {                  // 4 indices, then 4 gathers in flight
        int s0 = csr_src[e],     s1 = csr_src[e + 1];
        int sA = csr_src[e + 2], sB = csr_src[e + 3];
        float n0 = csr_norm[e],     n1 = csr_norm[e + 1];
        float n2 = csr_norm[e + 2], n3 = csr_norm[e + 3];
        unsigned int u0 = *(const unsigned int*)(h + (size_t)s0 * 128 + 2 * lane);
        unsigned int u1 = *(const unsigned int*)(h + (size_t)s1 * 128 + 2 * lane);
        unsigned int u2 = *(const unsigned int*)(h + (size_t)sA * 128 + 2 * lane);
        unsigned int u3 = *(const unsigned int*)(h + (size_t)sB * 128 + 2 * lane);
        a0 = fmaf(bf_lo(u0), n0, a0); a1 = fmaf(bf_hi(u0), n0, a1);
        a0 = fmaf(bf_lo(u1), n1, a0); a1 = fmaf(bf_hi(u1), n1, a1);
        a0 = fmaf(bf_lo(u2), n2, a0); a1 = fmaf(bf_hi(u2), n2, a1);
        a0 = fmaf(bf_lo(u3), n3, a0); a1 = fmaf(bf_hi(u3), n3, a1);
    }
    for (; e < end; ++e) {
        int s = csr_src[e];
        float n = csr_norm[e];
        unsigned int u = *(const unsigned int*)(h + (size_t)s * 128 + 2 * lane);
        a0 = fmaf(bf_lo(u), n, a0);
        a1 = fmaf(bf_hi(u), n, a1);
    }
    unsigned int w = ((unsigned int)f2bf(a1) << 16) | (unsigned int)f2bf(a0);
    *(unsigned int*)(out + (size_t)wid * 128 + 2 * lane) = w;
}

// ---------------------------------------------------------------- aggregation F=64 + bias + relu + Wl dot
__global__ __launch_bounds__(256) void k_agg64_dot(const float* __restrict__ h,
                                                   const float* __restrict__ dis,
                                                   const int* __restrict__ row_ptr,
                                                   const int* __restrict__ csr_src,
                                                   const float* __restrict__ csr_norm,
                                                   const float* __restrict__ bias,
                                                   const float* __restrict__ Wl,
                                                   float* __restrict__ s_out) {
    int wid = (blockIdx.x * 256 + threadIdx.x) >> 6;
    int lane = threadIdx.x & 63;
    if (wid >= N_NODES) return;
    int beg = row_ptr[wid], end = row_ptr[wid + 1];
    float d = dis[wid], s2 = d * d;
    float a0 = h[(size_t)wid * 64 + lane] * s2;
    int e = beg;
    for (; e + 4 <= end; e += 4) {
        int s0 = csr_src[e],     s1 = csr_src[e + 1];
        int sA = csr_src[e + 2], sB = csr_src[e + 3];
        float n0 = csr_norm[e],     n1 = csr_norm[e + 1];
        float n2 = csr_norm[e + 2], n3 = csr_norm[e + 3];
        float x0 = h[(size_t)s0 * 64 + lane];
        float x1 = h[(size_t)s1 * 64 + lane];
        float x2 = h[(size_t)sA * 64 + lane];
        float x3 = h[(size_t)sB * 64 + lane];
        a0 = fmaf(x0, n0, a0);
        a0 = fmaf(x1, n1, a0);
        a0 = fmaf(x2, n2, a0);
        a0 = fmaf(x3, n3, a0);
    }
    for (; e < end; ++e) {
        a0 = fmaf(h[(size_t)csr_src[e] * 64 + lane], csr_norm[e], a0);
    }
    float v = fmaxf(a0 + bias[lane], 0.0f) * Wl[lane];
    #pragma unroll
    for (int off = 32; off > 0; off >>= 1) v += __shfl_down(v, off, 64);
    if (lane == 0) s_out[wid] = v;
}

// ---------------------------------------------------------------- pack W [128 x N] fp32 into MFMA B-frag order
// packed[((ct*4 + ks)*64 + lane)*8 + j] = bf16( W[ks*32 + (lane>>4)*8 + j][ct*16 + (lane&15)] )
template <int N>
__global__ void k_pack_w(const float* __restrict__ W, unsigned short* __restrict__ out) {
    constexpr int TOT = (N / 16) * 4 * 64;
    int idx = blockIdx.x * 256 + threadIdx.x;
    if (idx >= TOT) return;
    int lane = idx & 63;
    int ks = (idx >> 6) & 3;
    int ct = idx >> 8;
    int n = ct * 16 + (lane & 15);
    int kbase = ks * 32 + (lane >> 4) * 8;
    #pragma unroll
    for (int j = 0; j < 8; ++j)
        out[(size_t)idx * 8 + j] = f2bf(W[(size_t)(kbase + j) * N + n]);
}

// ---------------------------------------------------------------- bf16 MFMA GEMM: [M,128] @ [128,N]
// No LDS: A rows are natively A-frag order (K contiguous), W pre-packed to B-frag order.
// Block = 4 waves; each wave computes 32 rows x N.
template <int N, bool BIAS_RELU, bool OUT_BF16>
__global__ __launch_bounds__(256) void k_gemm_mfma(const unsigned short* __restrict__ A,
                                                   const unsigned short* __restrict__ Wp,
                                                   const float* __restrict__ bias,
                                                   void* __restrict__ Cv) {
    constexpr int K = 128, NCT = N / 16, NKS = 4, MT = 2;
    int wave = threadIdx.x >> 6, lane = threadIdx.x & 63;
    int quad = lane >> 4, m16 = lane & 15;
    long base = (long)blockIdx.x * (64 * MT) + wave * (16 * MT);

    const short8 zero8 = {0, 0, 0, 0, 0, 0, 0, 0};
    short8 af[MT][NKS];
    #pragma unroll
    for (int mt = 0; mt < MT; ++mt) {
        long row = base + mt * 16 + m16;
        const unsigned short* ar = A + row * K;
        bool ok = row < N_NODES;
        #pragma unroll
        for (int ks = 0; ks < NKS; ++ks)
            af[mt][ks] = ok ? *(const short8*)(ar + ks * 32 + quad * 8) : zero8;
    }

    floatx4 acc[MT][NCT];
    #pragma unroll
    for (int mt = 0; mt < MT; ++mt)
        #pragma unroll
        for (int ct = 0; ct < NCT; ++ct)
            acc[mt][ct] = (floatx4){0.f, 0.f, 0.f, 0.f};

    #pragma unroll
    for (int ct = 0; ct < NCT; ++ct) {
        #pragma unroll
        for (int ks = 0; ks < NKS; ++ks) {
            short8 bf = *(const short8*)(Wp + ((size_t)(ct * NKS + ks) * 64 + lane) * 8);
            #pragma unroll
            for (int mt = 0; mt < MT; ++mt)
                acc[mt][ct] = __builtin_amdgcn_mfma_f32_16x16x32_bf16(
                    af[mt][ks], bf, acc[mt][ct], 0, 0, 0);
        }
    }

    // epilogue: C/D layout col=lane&15, row=quad*4+r (verified m89/m91)
    #pragma unroll
    for (int mt = 0; mt < MT; ++mt) {
        #pragma unroll
        for (int ct = 0; ct < NCT; ++ct) {
            int col = ct * 16 + m16;
            float bv = BIAS_RELU ? bias[col] : 0.0f;
            #pragma unroll
            for (int r = 0; r < 4; ++r) {
                long row = base + mt * 16 + quad * 4 + r;
                if (row < N_NODES) {
                    float v = acc[mt][ct][r];
                    if (BIAS_RELU) v = fmaxf(v + bv, 0.0f);
                    if (OUT_BF16)
                        ((unsigned short*)Cv)[row * N + col] = f2bf(v);
                    else
                        ((float*)Cv)[row * N + col] = v;
                }
            }
        }
    }
}

// ---------------------------------------------------------------- pool over per-node scalars
__global__ __launch_bounds__(256) void k_pool2(const float* __restrict__ s,
                                               const int* __restrict__ batch,
                                               const float* __restrict__ bl,
                                               float* __restrict__ out) {
    int g = blockIdx.x;
    int tid = threadIdx.x;
    int lo = 0, hi = N_NODES;
    while (lo < hi) { int m = (lo + hi) >> 1; if (batch[m] < g) lo = m + 1; else hi = m; }
    int lo2 = lo, hi2 = N_NODES;
    while (lo2 < hi2) { int m = (lo2 + hi2) >> 1; if (batch[m] < g + 1) lo2 = m + 1; else hi2 = m; }
    float acc = 0.0f;
    for (int n = lo + tid; n < lo2; n += 256) acc += s[n];
    __shared__ float sm[256];
    sm[tid] = acc; __syncthreads();
    for (int off = 128; off > 0; off >>= 1) {
        if (tid < off) sm[tid] += sm[tid + off];
        __syncthreads();
    }
    if (tid == 0) out[g] = sm[0] / fmaxf((float)(lo2 - lo), 1.0f) + bl[0];
}

// ---------------------------------------------------------------- launcher
extern "C" void kernel_launch(void* const* d_in, const int* in_sizes, int n_in,
                              void* d_out, int out_size, void* d_ws, size_t ws_size,
                              hipStream_t stream) {
    const float* x     = (const float*)d_in[0];
    const int*   ei    = (const int*)d_in[1];     // [0..E) = src, [E..2E) = dst
    const int*   batch = (const int*)d_in[2];
    const float* W1 = (const float*)d_in[3];
    const float* b1 = (const float*)d_in[4];
    const float* W2 = (const float*)d_in[5];
    const float* b2 = (const float*)d_in[6];
    const float* W3 = (const float*)d_in[7];
    const float* b3 = (const float*)d_in[8];
    const float* Wl = (const float*)d_in[9];
    const float* bl = (const float*)d_in[10];
    float* out = (float*)d_out;

    const int* e_src = ei;
    const int* e_dst = ei + N_EDGES;

    char* ws = (char*)d_ws;
    size_t off = 0;
    auto alloc = [&](size_t bytes) -> char* {
        char* p = ws + off;
        off = (off + bytes + 255) & ~(size_t)255;
        return p;
    };
    int*   cnt      = (int*)  alloc((size_t)N_NODES * 4);
    float* dis      = (float*)alloc((size_t)N_NODES * 4);
    int*   row_ptr  = (int*)  alloc((size_t)(N_NODES + 1) * 4);
    int*   cursor   = (int*)  alloc((size_t)N_NODES * 4);
    int*   part     = (int*)  alloc(1024 * 4);
    int*   csr_src  = (int*)  alloc((size_t)N_EDGES * 4);
    float* csr_norm = (float*)alloc((size_t)N_EDGES * 4);
    float* agg1     = (float*)alloc((size_t)N_NODES * 3 * 4);
    float* nscal    = (float*)alloc((size_t)N_NODES * 4);
    unsigned short* P1b = (unsigned short*)alloc((size_t)N_NODES * 128 * 2); // h1 bf16
    unsigned short* Qb  = (unsigned short*)alloc((size_t)N_NODES * 128 * 2); // agg(h1) bf16
    unsigned short* P2b = (unsigned short*)alloc((size_t)N_NODES * 128 * 2); // h2 bf16
    float*          Q2f = (float*)         alloc((size_t)N_NODES * 64 * 4); // h2@W3 fp32
    unsigned short* Wp2 = (unsigned short*)alloc((size_t)128 * 128 * 2);
    unsigned short* Wp3 = (unsigned short*)alloc((size_t)128 * 64 * 2);

    const int NB_N = (N_NODES + 255) / 256;   // 391
    const int NB_E = (N_EDGES + 255) / 256;

    k_init_cnt<<<NB_N, 256, 0, stream>>>(cnt);
    k_hist<<<NB_E, 256, 0, stream>>>(e_dst, cnt);
    k_dis<<<NB_N, 256, 0, stream>>>(cnt, dis);
    k_scan1<<<NB_N, 256, 0, stream>>>(cnt, part);
    k_scan2<<<1, 512, 0, stream>>>(part, row_ptr, NB_N);
    k_scan3<<<NB_N, 256, 0, stream>>>(cnt, part, row_ptr, cursor);
    k_scatter<<<NB_E, 256, 0, stream>>>(e_src, e_dst, dis, cursor, csr_src, csr_norm);

    // pack weights to MFMA B-fragment order (bf16)
    k_pack_w<128><<<8, 256, 0, stream>>>(W2, Wp2);
    k_pack_w<64><<<4, 256, 0, stream>>>(W3, Wp3);

    // layer 1: aggregate(F=3) -> GEMM 3->128 + b1 + relu -> bf16
    k_agg_f3<<<NB_N, 256, 0, stream>>>(x, dis, row_ptr, csr_src, csr_norm, agg1);
    k_gemm1<<<(N_NODES + 7) / 8, 256, 0, stream>>>(agg1, W1, b1, P1b);

    // layer 2: aggregate(F=128, bf16) -> MFMA GEMM 128->128 + b2 + relu -> bf16
    k_agg128_bf16<<<(N_NODES + 3) / 4, 256, 0, stream>>>(P1b, dis, row_ptr, csr_src, csr_norm, Qb);
    k_gemm_mfma<128, true, true><<<(N_NODES + 127) / 128, 256, 0, stream>>>(Qb, Wp2, b2, P2b);

    // layer 3: MFMA GEMM 128->64 (no bias) -> fp32, then aggregate(F=64)+b3+relu+dot(Wl)
    k_gemm_mfma<64, false, false><<<(N_NODES + 127) / 128, 256, 0, stream>>>(P2b, Wp3, nullptr, Q2f);
    k_agg64_dot<<<(N_NODES + 3) / 4, 256, 0, stream>>>(Q2f, dis, row_ptr, csr_src, csr_norm,
                                                       b3, Wl, nscal);

    // mean pool (+ bl) over per-node scalars
    k_pool2<<<N_GRAPHS, 256, 0, stream>>>(nscal, batch, bl, out);
}

// Round 5
// 279.287 us; speedup vs baseline: 1.7220x; 1.0631x over previous
//
#include <hip/hip_runtime.h>

#define N_NODES 100000
#define N_EDGES 600000
#define N_GRAPHS 512

typedef __attribute__((ext_vector_type(8))) short short8;
typedef __attribute__((ext_vector_type(4))) float floatx4;

__device__ __forceinline__ unsigned short f2bf(float f) {   // RNE f32 -> bf16
    unsigned int u = __float_as_uint(f);
    u += 0x7FFFu + ((u >> 16) & 1u);
    return (unsigned short)(u >> 16);
}
__device__ __forceinline__ float bf_lo(unsigned int u) { return __uint_as_float(u << 16); }
__device__ __forceinline__ float bf_hi(unsigned int u) { return __uint_as_float(u & 0xFFFF0000u); }
__device__ __forceinline__ float bf1(unsigned short u) { return __uint_as_float((unsigned int)u << 16); }

// ---------------------------------------------------------------- degree
__global__ void k_init_cnt(int* cnt) {
    int i = blockIdx.x * 256 + threadIdx.x;
    if (i < N_NODES) cnt[i] = 1;             // self-loop contributes 1 to deg
}

__global__ void k_hist(const int* __restrict__ dst, int* cnt) {
    int e = blockIdx.x * 256 + threadIdx.x;
    if (e < N_EDGES) atomicAdd(&cnt[dst[e]], 1);
}

__global__ void k_dis(const int* __restrict__ cnt, float* __restrict__ dis) {
    int i = blockIdx.x * 256 + threadIdx.x;
    if (i < N_NODES) dis[i] = 1.0f / sqrtf((float)cnt[i]);  // deg >= 1 always
}

// ---------------------------------------------------------------- scan (exclusive, over cnt[i]-1)
__global__ void k_scan1(const int* __restrict__ cnt, int* __restrict__ part) {
    __shared__ int s[256];
    int t = threadIdx.x;
    int i = blockIdx.x * 256 + t;
    int v = (i < N_NODES) ? cnt[i] - 1 : 0;
    s[t] = v; __syncthreads();
    for (int off = 128; off > 0; off >>= 1) {
        if (t < off) s[t] += s[t + off];
        __syncthreads();
    }
    if (t == 0) part[blockIdx.x] = s[0];
}

__global__ void k_scan2(int* __restrict__ part, int* __restrict__ row_ptr, int nb) {
    __shared__ int s[512];
    int t = threadIdx.x;
    int v = (t < nb) ? part[t] : 0;
    int orig = v;
    s[t] = v; __syncthreads();
    for (int off = 1; off < 512; off <<= 1) {
        int u = (t >= off) ? s[t - off] : 0;
        __syncthreads();
        s[t] += u;
        __syncthreads();
    }
    if (t < nb) part[t] = s[t] - orig;       // exclusive
    if (t == 0) row_ptr[N_NODES] = N_EDGES;
}

__global__ void k_scan3(const int* __restrict__ cnt, const int* __restrict__ part,
                        int* __restrict__ row_ptr, int* __restrict__ cursor) {
    __shared__ int s[256];
    int t = threadIdx.x;
    int i = blockIdx.x * 256 + t;
    int v = (i < N_NODES) ? cnt[i] - 1 : 0;
    s[t] = v; __syncthreads();
    for (int off = 1; off < 256; off <<= 1) {
        int u = (t >= off) ? s[t - off] : 0;
        __syncthreads();
        s[t] += u;
        __syncthreads();
    }
    int ex = s[t] - v + part[blockIdx.x];
    if (i < N_NODES) { row_ptr[i] = ex; cursor[i] = ex; }
}

// ---------------------------------------------------------------- CSR scatter
__global__ void k_scatter(const int* __restrict__ src, const int* __restrict__ dst,
                          const float* __restrict__ dis, int* __restrict__ cursor,
                          int* __restrict__ csr_src, float* __restrict__ csr_norm) {
    int e = blockIdx.x * 256 + threadIdx.x;
    if (e >= N_EDGES) return;
    int s = src[e], d = dst[e];
    int pos = atomicAdd(&cursor[d], 1);
    csr_src[pos] = s;
    csr_norm[pos] = dis[s] * dis[d];
}

// ---------------------------------------------------------------- aggregation F=3 (thread per node)
// masked 4-unroll: ceil(deg/4) iterations, no serial tail
__global__ void k_agg_f3(const float* __restrict__ x, const float* __restrict__ dis,
                         const int* __restrict__ row_ptr, const int* __restrict__ csr_src,
                         const float* __restrict__ csr_norm, float* __restrict__ out) {
    int i = blockIdx.x * 256 + threadIdx.x;
    if (i >= N_NODES) return;
    float d = dis[i], s2 = d * d;
    float a0 = x[i * 3 + 0] * s2;
    float a1 = x[i * 3 + 1] * s2;
    float a2 = x[i * 3 + 2] * s2;
    int beg = row_ptr[i], end = row_ptr[i + 1];
    for (int e = beg; e < end; e += 4) {
        int idx[4]; float nn[4];
        #pragma unroll
        for (int u = 0; u < 4; ++u) {
            int ee = e + u;
            int cl = ee < end ? ee : end - 1;
            idx[u] = csr_src[cl];
            nn[u] = ee < end ? csr_norm[cl] : 0.0f;
        }
        float xv[4][3];
        #pragma unroll
        for (int u = 0; u < 4; ++u) {
            xv[u][0] = x[idx[u] * 3 + 0];
            xv[u][1] = x[idx[u] * 3 + 1];
            xv[u][2] = x[idx[u] * 3 + 2];
        }
        #pragma unroll
        for (int u = 0; u < 4; ++u) {
            a0 = fmaf(xv[u][0], nn[u], a0);
            a1 = fmaf(xv[u][1], nn[u], a1);
            a2 = fmaf(xv[u][2], nn[u], a2);
        }
    }
    out[i * 3 + 0] = a0; out[i * 3 + 1] = a1; out[i * 3 + 2] = a2;
}

// ---------------------------------------------------------------- GEMM1: [N,3]@[3,128]+b, relu -> bf16
__global__ __launch_bounds__(256) void k_gemm1(const float* __restrict__ a,
                                               const float* __restrict__ W,
                                               const float* __restrict__ b,
                                               unsigned short* __restrict__ out) {
    __shared__ float Ws[384];
    __shared__ float bs[128];
    int tid = threadIdx.x;
    for (int i = tid; i < 384; i += 256) Ws[i] = W[i];
    if (tid < 128) bs[tid] = b[tid];
    __syncthreads();
    int node = blockIdx.x * 8 + (tid >> 5);
    int f4 = tid & 31;
    if (node >= N_NODES) return;
    float a0 = a[node * 3 + 0], a1 = a[node * 3 + 1], a2 = a[node * 3 + 2];
    ushort4 o;
    unsigned short* op = (unsigned short*)&o;
    #pragma unroll
    for (int j = 0; j < 4; ++j) {
        int f = f4 * 4 + j;
        float v = bs[f] + a0 * Ws[f] + a1 * Ws[128 + f] + a2 * Ws[256 + f];
        op[j] = f2bf(fmaxf(v, 0.0f));
    }
    *(ushort4*)(out + (size_t)node * 128 + f4 * 4) = o;
}

// ---------------------------------------------------------------- aggregation F=128 bf16 (wave per node)
// lane handles features 2*lane, 2*lane+1; masked 8-unroll
__global__ __launch_bounds__(256) void k_agg128_bf16(const unsigned short* __restrict__ h,
                                                     const float* __restrict__ dis,
                                                     const int* __restrict__ row_ptr,
                                                     const int* __restrict__ csr_src,
                                                     const float* __restrict__ csr_norm,
                                                     unsigned short* __restrict__ out) {
    int wid = (blockIdx.x * 256 + threadIdx.x) >> 6;
    int lane = threadIdx.x & 63;
    if (wid >= N_NODES) return;
    int beg = row_ptr[wid], end = row_ptr[wid + 1];
    float d = dis[wid], s2 = d * d;
    unsigned int su = *(const unsigned int*)(h + (size_t)wid * 128 + 2 * lane);
    float a0 = bf_lo(su) * s2;
    float a1 = bf_hi(su) * s2;
    for (int e = beg; e < end; e += 8) {
        int idx[8]; float nn[8];
        #pragma unroll
        for (int u = 0; u < 8; ++u) {
            int ee = e + u;
            int cl = ee < end ? ee : end - 1;
            idx[u] = csr_src[cl];
            nn[u] = ee < end ? csr_norm[cl] : 0.0f;
        }
        unsigned int uv[8];
        #pragma unroll
        for (int u = 0; u < 8; ++u)
            uv[u] = *(const unsigned int*)(h + (size_t)idx[u] * 128 + 2 * lane);
        #pragma unroll
        for (int u = 0; u < 8; ++u) {
            a0 = fmaf(bf_lo(uv[u]), nn[u], a0);
            a1 = fmaf(bf_hi(uv[u]), nn[u], a1);
        }
    }
    unsigned int w = ((unsigned int)f2bf(a1) << 16) | (unsigned int)f2bf(a0);
    *(unsigned int*)(out + (size_t)wid * 128 + 2 * lane) = w;
}

// ---------------------------------------------------------------- aggregation F=64 bf16 + bias + relu + Wl dot
// h3 never materialized: s_out[n] = relu(agg + b3) . Wl ; masked 8-unroll
__global__ __launch_bounds__(256) void k_agg64_dot(const unsigned short* __restrict__ h,
                                                   const float* __restrict__ dis,
                                                   const int* __restrict__ row_ptr,
                                                   const int* __restrict__ csr_src,
                                                   const float* __restrict__ csr_norm,
                                                   const float* __restrict__ bias,
                                                   const float* __restrict__ Wl,
                                                   float* __restrict__ s_out) {
    int wid = (blockIdx.x * 256 + threadIdx.x) >> 6;
    int lane = threadIdx.x & 63;
    if (wid >= N_NODES) return;
    int beg = row_ptr[wid], end = row_ptr[wid + 1];
    float d = dis[wid], s2 = d * d;
    float a0 = bf1(h[(size_t)wid * 64 + lane]) * s2;
    for (int e = beg; e < end; e += 8) {
        int idx[8]; float nn[8];
        #pragma unroll
        for (int u = 0; u < 8; ++u) {
            int ee = e + u;
            int cl = ee < end ? ee : end - 1;
            idx[u] = csr_src[cl];
            nn[u] = ee < end ? csr_norm[cl] : 0.0f;
        }
        unsigned short hv[8];
        #pragma unroll
        for (int u = 0; u < 8; ++u)
            hv[u] = h[(size_t)idx[u] * 64 + lane];
        #pragma unroll
        for (int u = 0; u < 8; ++u)
            a0 = fmaf(bf1(hv[u]), nn[u], a0);
    }
    float v = fmaxf(a0 + bias[lane], 0.0f) * Wl[lane];
    #pragma unroll
    for (int off = 32; off > 0; off >>= 1) v += __shfl_down(v, off, 64);
    if (lane == 0) s_out[wid] = v;
}

// ---------------------------------------------------------------- pack W [128 x N] fp32 into MFMA B-frag order
template <int N>
__global__ void k_pack_w(const float* __restrict__ W, unsigned short* __restrict__ out) {
    constexpr int TOT = (N / 16) * 4 * 64;
    int idx = blockIdx.x * 256 + threadIdx.x;
    if (idx >= TOT) return;
    int lane = idx & 63;
    int ks = (idx >> 6) & 3;
    int ct = idx >> 8;
    int n = ct * 16 + (lane & 15);
    int kbase = ks * 32 + (lane >> 4) * 8;
    #pragma unroll
    for (int j = 0; j < 8; ++j)
        out[(size_t)idx * 8 + j] = f2bf(W[(size_t)(kbase + j) * N + n]);
}

// ---------------------------------------------------------------- bf16 MFMA GEMM: [M,128] @ [128,N]
// No LDS: A rows natively A-frag order (K contiguous), W pre-packed to B-frag order.
template <int N, bool BIAS_RELU, bool OUT_BF16>
__global__ __launch_bounds__(256) void k_gemm_mfma(const unsigned short* __restrict__ A,
                                                   const unsigned short* __restrict__ Wp,
                                                   const float* __restrict__ bias,
                                                   void* __restrict__ Cv) {
    constexpr int K = 128, NCT = N / 16, NKS = 4, MT = 2;
    int wave = threadIdx.x >> 6, lane = threadIdx.x & 63;
    int quad = lane >> 4, m16 = lane & 15;
    long base = (long)blockIdx.x * (64 * MT) + wave * (16 * MT);

    const short8 zero8 = {0, 0, 0, 0, 0, 0, 0, 0};
    short8 af[MT][NKS];
    #pragma unroll
    for (int mt = 0; mt < MT; ++mt) {
        long row = base + mt * 16 + m16;
        const unsigned short* ar = A + row * K;
        bool ok = row < N_NODES;
        #pragma unroll
        for (int ks = 0; ks < NKS; ++ks)
            af[mt][ks] = ok ? *(const short8*)(ar + ks * 32 + quad * 8) : zero8;
    }

    floatx4 acc[MT][NCT];
    #pragma unroll
    for (int mt = 0; mt < MT; ++mt)
        #pragma unroll
        for (int ct = 0; ct < NCT; ++ct)
            acc[mt][ct] = (floatx4){0.f, 0.f, 0.f, 0.f};

    #pragma unroll
    for (int ct = 0; ct < NCT; ++ct) {
        #pragma unroll
        for (int ks = 0; ks < NKS; ++ks) {
            short8 bf = *(const short8*)(Wp + ((size_t)(ct * NKS + ks) * 64 + lane) * 8);
            #pragma unroll
            for (int mt = 0; mt < MT; ++mt)
                acc[mt][ct] = __builtin_amdgcn_mfma_f32_16x16x32_bf16(
                    af[mt][ks], bf, acc[mt][ct], 0, 0, 0);
        }
    }

    // epilogue: C/D layout col=lane&15, row=quad*4+r
    #pragma unroll
    for (int mt = 0; mt < MT; ++mt) {
        #pragma unroll
        for (int ct = 0; ct < NCT; ++ct) {
            int col = ct * 16 + m16;
            float bv = BIAS_RELU ? bias[col] : 0.0f;
            #pragma unroll
            for (int r = 0; r < 4; ++r) {
                long row = base + mt * 16 + quad * 4 + r;
                if (row < N_NODES) {
                    float v = acc[mt][ct][r];
                    if (BIAS_RELU) v = fmaxf(v + bv, 0.0f);
                    if (OUT_BF16)
                        ((unsigned short*)Cv)[row * N + col] = f2bf(v);
                    else
                        ((float*)Cv)[row * N + col] = v;
                }
            }
        }
    }
}

// ---------------------------------------------------------------- pool over per-node scalars
__global__ __launch_bounds__(256) void k_pool2(const float* __restrict__ s,
                                               const int* __restrict__ batch,
                                               const float* __restrict__ bl,
                                               float* __restrict__ out) {
    int g = blockIdx.x;
    int tid = threadIdx.x;
    int lo = 0, hi = N_NODES;
    while (lo < hi) { int m = (lo + hi) >> 1; if (batch[m] < g) lo = m + 1; else hi = m; }
    int lo2 = lo, hi2 = N_NODES;
    while (lo2 < hi2) { int m = (lo2 + hi2) >> 1; if (batch[m] < g + 1) lo2 = m + 1; else hi2 = m; }
    float acc = 0.0f;
    for (int n = lo + tid; n < lo2; n += 256) acc += s[n];
    __shared__ float sm[256];
    sm[tid] = acc; __syncthreads();
    for (int off = 128; off > 0; off >>= 1) {
        if (tid < off) sm[tid] += sm[tid + off];
        __syncthreads();
    }
    if (tid == 0) out[g] = sm[0] / fmaxf((float)(lo2 - lo), 1.0f) + bl[0];
}

// ---------------------------------------------------------------- launcher
extern "C" void kernel_launch(void* const* d_in, const int* in_sizes, int n_in,
                              void* d_out, int out_size, void* d_ws, size_t ws_size,
                              hipStream_t stream) {
    const float* x     = (const float*)d_in[0];
    const int*   ei    = (const int*)d_in[1];     // [0..E) = src, [E..2E) = dst
    const int*   batch = (const int*)d_in[2];
    const float* W1 = (const float*)d_in[3];
    const float* b1 = (const float*)d_in[4];
    const float* W2 = (const float*)d_in[5];
    const float* b2 = (const float*)d_in[6];
    const float* W3 = (const float*)d_in[7];
    const float* b3 = (const float*)d_in[8];
    const float* Wl = (const float*)d_in[9];
    const float* bl = (const float*)d_in[10];
    float* out = (float*)d_out;

    const int* e_src = ei;
    const int* e_dst = ei + N_EDGES;

    char* ws = (char*)d_ws;
    size_t off = 0;
    auto alloc = [&](size_t bytes) -> char* {
        char* p = ws + off;
        off = (off + bytes + 255) & ~(size_t)255;
        return p;
    };
    int*   cnt      = (int*)  alloc((size_t)N_NODES * 4);
    float* dis      = (float*)alloc((size_t)N_NODES * 4);
    int*   row_ptr  = (int*)  alloc((size_t)(N_NODES + 1) * 4);
    int*   cursor   = (int*)  alloc((size_t)N_NODES * 4);
    int*   part     = (int*)  alloc(1024 * 4);
    int*   csr_src  = (int*)  alloc((size_t)N_EDGES * 4);
    float* csr_norm = (float*)alloc((size_t)N_EDGES * 4);
    float* agg1     = (float*)alloc((size_t)N_NODES * 3 * 4);
    float* nscal    = (float*)alloc((size_t)N_NODES * 4);
    unsigned short* P1b = (unsigned short*)alloc((size_t)N_NODES * 128 * 2); // h1 bf16
    unsigned short* Qb  = (unsigned short*)alloc((size_t)N_NODES * 128 * 2); // agg(h1) bf16
    unsigned short* P2b = (unsigned short*)alloc((size_t)N_NODES * 128 * 2); // h2 bf16
    unsigned short* Q2b = (unsigned short*)alloc((size_t)N_NODES * 64 * 2);  // h2@W3 bf16
    unsigned short* Wp2 = (unsigned short*)alloc((size_t)128 * 128 * 2);
    unsigned short* Wp3 = (unsigned short*)alloc((size_t)128 * 64 * 2);

    const int NB_N = (N_NODES + 255) / 256;   // 391
    const int NB_E = (N_EDGES + 255) / 256;

    k_init_cnt<<<NB_N, 256, 0, stream>>>(cnt);
    k_hist<<<NB_E, 256, 0, stream>>>(e_dst, cnt);
    k_dis<<<NB_N, 256, 0, stream>>>(cnt, dis);
    k_scan1<<<NB_N, 256, 0, stream>>>(cnt, part);
    k_scan2<<<1, 512, 0, stream>>>(part, row_ptr, NB_N);
    k_scan3<<<NB_N, 256, 0, stream>>>(cnt, part, row_ptr, cursor);
    k_scatter<<<NB_E, 256, 0, stream>>>(e_src, e_dst, dis, cursor, csr_src, csr_norm);

    // pack weights to MFMA B-fragment order (bf16)
    k_pack_w<128><<<8, 256, 0, stream>>>(W2, Wp2);
    k_pack_w<64><<<4, 256, 0, stream>>>(W3, Wp3);

    // layer 1: aggregate(F=3) -> GEMM 3->128 + b1 + relu -> bf16
    k_agg_f3<<<NB_N, 256, 0, stream>>>(x, dis, row_ptr, csr_src, csr_norm, agg1);
    k_gemm1<<<(N_NODES + 7) / 8, 256, 0, stream>>>(agg1, W1, b1, P1b);

    // layer 2: aggregate(F=128, bf16) -> MFMA GEMM 128->128 + b2 + relu -> bf16
    k_agg128_bf16<<<(N_NODES + 3) / 4, 256, 0, stream>>>(P1b, dis, row_ptr, csr_src, csr_norm, Qb);
    k_gemm_mfma<128, true, true><<<(N_NODES + 127) / 128, 256, 0, stream>>>(Qb, Wp2, b2, P2b);

    // layer 3: MFMA GEMM 128->64 (no bias) -> bf16, then aggregate(F=64)+b3+relu+dot(Wl)
    k_gemm_mfma<64, false, true><<<(N_NODES + 127) / 128, 256, 0, stream>>>(P2b, Wp3, nullptr, Q2b);
    k_agg64_dot<<<(N_NODES + 3) / 4, 256, 0, stream>>>(Q2b, dis, row_ptr, csr_src, csr_norm,
                                                       b3, Wl, nscal);

    // mean pool (+ bl) over per-node scalars
    k_pool2<<<N_GRAPHS, 256, 0, stream>>>(nscal, batch, bl, out);
}

// Round 6
// 273.691 us; speedup vs baseline: 1.7572x; 1.0204x over previous
//
#include <hip/hip_runtime.h>

#define N_NODES 100000
#define N_EDGES 600000
#define N_GRAPHS 512

typedef __attribute__((ext_vector_type(8))) short short8;
typedef __attribute__((ext_vector_type(4))) float floatx4;

__device__ __forceinline__ unsigned short f2bf(float f) {   // RNE f32 -> bf16
    unsigned int u = __float_as_uint(f);
    u += 0x7FFFu + ((u >> 16) & 1u);
    return (unsigned short)(u >> 16);
}
__device__ __forceinline__ float bf_lo(unsigned int u) { return __uint_as_float(u << 16); }
__device__ __forceinline__ float bf_hi(unsigned int u) { return __uint_as_float(u & 0xFFFF0000u); }
__device__ __forceinline__ float bf1(unsigned short u) { return __uint_as_float((unsigned int)u << 16); }

// ---------------------------------------------------------------- degree hist (cnt zeroed by memset)
__global__ void k_hist(const int* __restrict__ dst, int* cnt) {
    int e = blockIdx.x * 256 + threadIdx.x;
    if (e < N_EDGES) atomicAdd(&cnt[dst[e]], 1);
}

// ---------------------------------------------------------------- scan (exclusive over cnt; deg = cnt+1)
__global__ void k_scan1(const int* __restrict__ cnt, int* __restrict__ part) {
    __shared__ int s[256];
    int t = threadIdx.x;
    int i = blockIdx.x * 256 + t;
    int v = (i < N_NODES) ? cnt[i] : 0;
    s[t] = v; __syncthreads();
    for (int off = 128; off > 0; off >>= 1) {
        if (t < off) s[t] += s[t + off];
        __syncthreads();
    }
    if (t == 0) part[blockIdx.x] = s[0];
}

__global__ void k_scan2(int* __restrict__ part, int* __restrict__ row_ptr, int nb) {
    __shared__ int s[512];
    int t = threadIdx.x;
    int v = (t < nb) ? part[t] : 0;
    int orig = v;
    s[t] = v; __syncthreads();
    for (int off = 1; off < 512; off <<= 1) {
        int u = (t >= off) ? s[t - off] : 0;
        __syncthreads();
        s[t] += u;
        __syncthreads();
    }
    if (t < nb) part[t] = s[t] - orig;       // exclusive
    if (t == 0) row_ptr[N_NODES] = N_EDGES;
}

// scan3 also emits cursor and dis (k_dis folded in)
__global__ void k_scan3(const int* __restrict__ cnt, const int* __restrict__ part,
                        int* __restrict__ row_ptr, int* __restrict__ cursor,
                        float* __restrict__ dis) {
    __shared__ int s[256];
    int t = threadIdx.x;
    int i = blockIdx.x * 256 + t;
    int v = (i < N_NODES) ? cnt[i] : 0;
    s[t] = v; __syncthreads();
    for (int off = 1; off < 256; off <<= 1) {
        int u = (t >= off) ? s[t - off] : 0;
        __syncthreads();
        s[t] += u;
        __syncthreads();
    }
    int ex = s[t] - v + part[blockIdx.x];
    if (i < N_NODES) {
        row_ptr[i] = ex; cursor[i] = ex;
        dis[i] = 1.0f / sqrtf((float)(v + 1));   // deg includes self-loop
    }
}

// ---------------------------------------------------------------- CSR scatter
__global__ void k_scatter(const int* __restrict__ src, const int* __restrict__ dst,
                          const float* __restrict__ dis, int* __restrict__ cursor,
                          int* __restrict__ csr_src, float* __restrict__ csr_norm) {
    int e = blockIdx.x * 256 + threadIdx.x;
    if (e >= N_EDGES) return;
    int s = src[e], d = dst[e];
    int pos = atomicAdd(&cursor[d], 1);
    csr_src[pos] = s;
    csr_norm[pos] = dis[s] * dis[d];
}

// ---------------------------------------------------------------- pack W2 [128x128] and W3 [128x64] to B-frag order
__device__ __forceinline__ void pack_one(const float* __restrict__ W, unsigned short* __restrict__ out,
                                         int idx, int N) {
    int lane = idx & 63;
    int ks = (idx >> 6) & 3;
    int ct = idx >> 8;
    int n = ct * 16 + (lane & 15);
    int kbase = ks * 32 + (lane >> 4) * 8;
    #pragma unroll
    for (int j = 0; j < 8; ++j)
        out[(size_t)idx * 8 + j] = f2bf(W[(size_t)(kbase + j) * N + n]);
}

__global__ void k_pack_w_both(const float* __restrict__ W2, const float* __restrict__ W3,
                              unsigned short* __restrict__ Wp2, unsigned short* __restrict__ Wp3) {
    int idx = blockIdx.x * 256 + threadIdx.x;        // 12 blocks = 3072
    if (idx < 2048) pack_one(W2, Wp2, idx, 128);     // 8 ct * 4 ks * 64
    else if (idx < 3072) pack_one(W3, Wp3, idx - 2048, 64);
}

// ---------------------------------------------------------------- layer 1 fused: agg(F=3, edge-parallel) + GEMM 3->128 + b1 + relu -> bf16
// wave per node; lanes split edges, butterfly-reduce 3 sums; then 2 outputs/lane.
__global__ __launch_bounds__(256) void k_node1(const float* __restrict__ x,
                                               const float* __restrict__ dis,
                                               const int* __restrict__ row_ptr,
                                               const int* __restrict__ csr_src,
                                               const float* __restrict__ csr_norm,
                                               const float* __restrict__ W1,
                                               const float* __restrict__ b1,
                                               unsigned short* __restrict__ out) {
    __shared__ float Ws[384];
    __shared__ float bs[128];
    int tid = threadIdx.x;
    for (int i = tid; i < 384; i += 256) Ws[i] = W1[i];
    if (tid < 128) bs[tid] = b1[tid];
    __syncthreads();
    int wid = (blockIdx.x * 256 + tid) >> 6;
    int lane = tid & 63;
    if (wid >= N_NODES) return;
    int beg = row_ptr[wid], end = row_ptr[wid + 1];
    float p0 = 0.f, p1 = 0.f, p2 = 0.f;
    for (int e = beg + lane; e < end; e += 64) {
        int s = csr_src[e];
        float n = csr_norm[e];
        p0 = fmaf(x[s * 3 + 0], n, p0);
        p1 = fmaf(x[s * 3 + 1], n, p1);
        p2 = fmaf(x[s * 3 + 2], n, p2);
    }
    #pragma unroll
    for (int m = 32; m > 0; m >>= 1) {          // butterfly: all lanes get totals
        p0 += __shfl_xor(p0, m, 64);
        p1 += __shfl_xor(p1, m, 64);
        p2 += __shfl_xor(p2, m, 64);
    }
    float d = dis[wid], s2 = d * d;
    float a0 = fmaf(x[wid * 3 + 0], s2, p0);
    float a1 = fmaf(x[wid * 3 + 1], s2, p1);
    float a2 = fmaf(x[wid * 3 + 2], s2, p2);
    int f = 2 * lane;
    float v0 = bs[f]     + a0 * Ws[f]     + a1 * Ws[128 + f]     + a2 * Ws[256 + f];
    float v1 = bs[f + 1] + a0 * Ws[f + 1] + a1 * Ws[128 + f + 1] + a2 * Ws[256 + f + 1];
    unsigned int w = ((unsigned int)f2bf(fmaxf(v1, 0.f)) << 16) | (unsigned int)f2bf(fmaxf(v0, 0.f));
    *(unsigned int*)(out + (size_t)wid * 128 + f) = w;
}

// ---------------------------------------------------------------- layers 2+3 fused:
// agg(F=128 bf16) -> LDS -> MFMA GEMM2 (+b2, relu) -> LDS -> MFMA GEMM3 -> Q2b bf16
// block = 32 nodes (100000 = 3125 * 32, exact). LDS rows padded to 136 ushorts (16B-aligned).
__global__ __launch_bounds__(256) void k_layer23(const unsigned short* __restrict__ h1,
                                                 const float* __restrict__ dis,
                                                 const int* __restrict__ row_ptr,
                                                 const int* __restrict__ csr_src,
                                                 const float* __restrict__ csr_norm,
                                                 const unsigned short* __restrict__ Wp2,
                                                 const float* __restrict__ b2,
                                                 const unsigned short* __restrict__ Wp3,
                                                 unsigned short* __restrict__ Q2b) {
    __shared__ unsigned short Asb[32][136];   // aggregated h1 tile
    __shared__ unsigned short Hsb[32][136];   // h2 tile
    int tid = threadIdx.x;
    int wave = tid >> 6, lane = tid & 63;
    int quad = lane >> 4, m16 = lane & 15;
    int base = blockIdx.x * 32;

    // ---- phase 1: wave aggregates 8 nodes, feature-parallel (2 feats/lane)
    for (int r8 = 0; r8 < 8; ++r8) {
        int r = wave * 8 + r8;
        int node = base + r;
        int beg = row_ptr[node], end = row_ptr[node + 1];
        float d = dis[node], s2 = d * d;
        unsigned int su = *(const unsigned int*)(h1 + (size_t)node * 128 + 2 * lane);
        float a0 = bf_lo(su) * s2;
        float a1 = bf_hi(su) * s2;
        for (int e = beg; e < end; e += 8) {
            int idx[8]; float nn[8];
            #pragma unroll
            for (int u = 0; u < 8; ++u) {
                int ee = e + u;
                int cl = ee < end ? ee : end - 1;
                idx[u] = csr_src[cl];
                nn[u] = ee < end ? csr_norm[cl] : 0.0f;
            }
            unsigned int uv[8];
            #pragma unroll
            for (int u = 0; u < 8; ++u)
                uv[u] = *(const unsigned int*)(h1 + (size_t)idx[u] * 128 + 2 * lane);
            #pragma unroll
            for (int u = 0; u < 8; ++u) {
                a0 = fmaf(bf_lo(uv[u]), nn[u], a0);
                a1 = fmaf(bf_hi(uv[u]), nn[u], a1);
            }
        }
        unsigned int w = ((unsigned int)f2bf(a1) << 16) | (unsigned int)f2bf(a0);
        *(unsigned int*)(&Asb[r][2 * lane]) = w;
    }
    __syncthreads();

    // ---- phase 2: 32x128 = Asb(32x128) @ Wp2(128x128), +b2, relu -> Hsb
    int mt = wave & 1;                 // row tile (16 rows)
    int ch = wave >> 1;                // column half (64 cols)
    {
        short8 af[4];
        #pragma unroll
        for (int ks = 0; ks < 4; ++ks)
            af[ks] = *(const short8*)(&Asb[mt * 16 + m16][ks * 32 + quad * 8]);
        floatx4 acc[4];
        #pragma unroll
        for (int ct = 0; ct < 4; ++ct) acc[ct] = (floatx4){0.f, 0.f, 0.f, 0.f};
        #pragma unroll
        for (int ct = 0; ct < 4; ++ct) {
            int gct = ch * 4 + ct;
            #pragma unroll
            for (int ks = 0; ks < 4; ++ks) {
                short8 bf = *(const short8*)(Wp2 + ((size_t)(gct * 4 + ks) * 64 + lane) * 8);
                acc[ct] = __builtin_amdgcn_mfma_f32_16x16x32_bf16(af[ks], bf, acc[ct], 0, 0, 0);
            }
        }
        #pragma unroll
        for (int ct = 0; ct < 4; ++ct) {
            int col = (ch * 4 + ct) * 16 + m16;
            float bv = b2[col];
            #pragma unroll
            for (int r = 0; r < 4; ++r) {
                int row = mt * 16 + quad * 4 + r;
                Hsb[row][col] = f2bf(fmaxf(acc[ct][r] + bv, 0.0f));
            }
        }
    }
    __syncthreads();

    // ---- phase 3: 32x64 = Hsb(32x128) @ Wp3(128x64) -> global Q2b (bf16, no bias)
    {
        int cp = wave >> 1;            // column pair (32 cols)
        short8 hf[4];
        #pragma unroll
        for (int ks = 0; ks < 4; ++ks)
            hf[ks] = *(const short8*)(&Hsb[mt * 16 + m16][ks * 32 + quad * 8]);
        floatx4 acc3[2];
        acc3[0] = (floatx4){0.f, 0.f, 0.f, 0.f};
        acc3[1] = (floatx4){0.f, 0.f, 0.f, 0.f};
        #pragma unroll
        for (int ct = 0; ct < 2; ++ct) {
            int gct = cp * 2 + ct;
            #pragma unroll
            for (int ks = 0; ks < 4; ++ks) {
                short8 bf = *(const short8*)(Wp3 + ((size_t)(gct * 4 + ks) * 64 + lane) * 8);
                acc3[ct] = __builtin_amdgcn_mfma_f32_16x16x32_bf16(hf[ks], bf, acc3[ct], 0, 0, 0);
            }
        }
        #pragma unroll
        for (int ct = 0; ct < 2; ++ct) {
            int col = (cp * 2 + ct) * 16 + m16;
            #pragma unroll
            for (int r = 0; r < 4; ++r) {
                long row = base + mt * 16 + quad * 4 + r;
                Q2b[row * 64 + col] = f2bf(acc3[ct][r]);
            }
        }
    }
}

// ---------------------------------------------------------------- aggregation F=64 bf16 + bias + relu + Wl dot
__global__ __launch_bounds__(256) void k_agg64_dot(const unsigned short* __restrict__ h,
                                                   const float* __restrict__ dis,
                                                   const int* __restrict__ row_ptr,
                                                   const int* __restrict__ csr_src,
                                                   const float* __restrict__ csr_norm,
                                                   const float* __restrict__ bias,
                                                   const float* __restrict__ Wl,
                                                   float* __restrict__ s_out) {
    int wid = (blockIdx.x * 256 + threadIdx.x) >> 6;
    int lane = threadIdx.x & 63;
    if (wid >= N_NODES) return;
    int beg = row_ptr[wid], end = row_ptr[wid + 1];
    float d = dis[wid], s2 = d * d;
    float a0 = bf1(h[(size_t)wid * 64 + lane]) * s2;
    for (int e = beg; e < end; e += 8) {
        int idx[8]; float nn[8];
        #pragma unroll
        for (int u = 0; u < 8; ++u) {
            int ee = e + u;
            int cl = ee < end ? ee : end - 1;
            idx[u] = csr_src[cl];
            nn[u] = ee < end ? csr_norm[cl] : 0.0f;
        }
        unsigned short hv[8];
        #pragma unroll
        for (int u = 0; u < 8; ++u)
            hv[u] = h[(size_t)idx[u] * 64 + lane];
        #pragma unroll
        for (int u = 0; u < 8; ++u)
            a0 = fmaf(bf1(hv[u]), nn[u], a0);
    }
    float v = fmaxf(a0 + bias[lane], 0.0f) * Wl[lane];
    #pragma unroll
    for (int off = 32; off > 0; off >>= 1) v += __shfl_down(v, off, 64);
    if (lane == 0) s_out[wid] = v;
}

// ---------------------------------------------------------------- pool over per-node scalars
__global__ __launch_bounds__(256) void k_pool2(const float* __restrict__ s,
                                               const int* __restrict__ batch,
                                               const float* __restrict__ bl,
                                               float* __restrict__ out) {
    int g = blockIdx.x;
    int tid = threadIdx.x;
    int lo = 0, hi = N_NODES;
    while (lo < hi) { int m = (lo + hi) >> 1; if (batch[m] < g) lo = m + 1; else hi = m; }
    int lo2 = lo, hi2 = N_NODES;
    while (lo2 < hi2) { int m = (lo2 + hi2) >> 1; if (batch[m] < g + 1) lo2 = m + 1; else hi2 = m; }
    float acc = 0.0f;
    for (int n = lo + tid; n < lo2; n += 256) acc += s[n];
    __shared__ float sm[256];
    sm[tid] = acc; __syncthreads();
    for (int off = 128; off > 0; off >>= 1) {
        if (tid < off) sm[tid] += sm[tid + off];
        __syncthreads();
    }
    if (tid == 0) out[g] = sm[0] / fmaxf((float)(lo2 - lo), 1.0f) + bl[0];
}

// ---------------------------------------------------------------- launcher
extern "C" void kernel_launch(void* const* d_in, const int* in_sizes, int n_in,
                              void* d_out, int out_size, void* d_ws, size_t ws_size,
                              hipStream_t stream) {
    const float* x     = (const float*)d_in[0];
    const int*   ei    = (const int*)d_in[1];     // [0..E) = src, [E..2E) = dst
    const int*   batch = (const int*)d_in[2];
    const float* W1 = (const float*)d_in[3];
    const float* b1 = (const float*)d_in[4];
    const float* W2 = (const float*)d_in[5];
    const float* b2 = (const float*)d_in[6];
    const float* W3 = (const float*)d_in[7];
    const float* b3 = (const float*)d_in[8];
    const float* Wl = (const float*)d_in[9];
    const float* bl = (const float*)d_in[10];
    float* out = (float*)d_out;

    const int* e_src = ei;
    const int* e_dst = ei + N_EDGES;

    char* ws = (char*)d_ws;
    size_t off = 0;
    auto alloc = [&](size_t bytes) -> char* {
        char* p = ws + off;
        off = (off + bytes + 255) & ~(size_t)255;
        return p;
    };
    int*   cnt      = (int*)  alloc((size_t)N_NODES * 4);
    float* dis      = (float*)alloc((size_t)N_NODES * 4);
    int*   row_ptr  = (int*)  alloc((size_t)(N_NODES + 1) * 4);
    int*   cursor   = (int*)  alloc((size_t)N_NODES * 4);
    int*   part     = (int*)  alloc(1024 * 4);
    int*   csr_src  = (int*)  alloc((size_t)N_EDGES * 4);
    float* csr_norm = (float*)alloc((size_t)N_EDGES * 4);
    float* nscal    = (float*)alloc((size_t)N_NODES * 4);
    unsigned short* P1b = (unsigned short*)alloc((size_t)N_NODES * 128 * 2); // h1 bf16
    unsigned short* Q2b = (unsigned short*)alloc((size_t)N_NODES * 64 * 2);  // h2@W3 bf16
    unsigned short* Wp2 = (unsigned short*)alloc((size_t)128 * 128 * 2);
    unsigned short* Wp3 = (unsigned short*)alloc((size_t)128 * 64 * 2);

    const int NB_N = (N_NODES + 255) / 256;   // 391
    const int NB_E = (N_EDGES + 255) / 256;

    hipMemsetAsync(cnt, 0, (size_t)N_NODES * 4, stream);
    k_hist<<<NB_E, 256, 0, stream>>>(e_dst, cnt);
    k_scan1<<<NB_N, 256, 0, stream>>>(cnt, part);
    k_scan2<<<1, 512, 0, stream>>>(part, row_ptr, NB_N);
    k_scan3<<<NB_N, 256, 0, stream>>>(cnt, part, row_ptr, cursor, dis);
    k_scatter<<<NB_E, 256, 0, stream>>>(e_src, e_dst, dis, cursor, csr_src, csr_norm);
    k_pack_w_both<<<12, 256, 0, stream>>>(W2, W3, Wp2, Wp3);

    // layer 1 fused: agg(F=3) + GEMM 3->128 + b1 + relu -> bf16
    k_node1<<<(N_NODES * 64 + 255) / 256, 256, 0, stream>>>(x, dis, row_ptr, csr_src, csr_norm,
                                                            W1, b1, P1b);

    // layers 2+3 fused: agg(F=128) + GEMM2(+b2,relu) + GEMM3 -> Q2b bf16
    k_layer23<<<N_NODES / 32, 256, 0, stream>>>(P1b, dis, row_ptr, csr_src, csr_norm,
                                                Wp2, b2, Wp3, Q2b);

    // layer 3 aggregation + b3 + relu + dot(Wl)
    k_agg64_dot<<<(N_NODES + 3) / 4, 256, 0, stream>>>(Q2b, dis, row_ptr, csr_src, csr_norm,
                                                       b3, Wl, nscal);

    // mean pool (+ bl) over per-node scalars
    k_pool2<<<N_GRAPHS, 256, 0, stream>>>(nscal, batch, bl, out);
}

// Round 7
// 256.525 us; speedup vs baseline: 1.8748x; 1.0669x over previous
//
#include <hip/hip_runtime.h>

#define N_NODES 100000
#define N_EDGES 600000
#define N_GRAPHS 512

typedef __attribute__((ext_vector_type(8))) short short8;
typedef __attribute__((ext_vector_type(4))) float floatx4;

__device__ __forceinline__ unsigned short f2bf(float f) {   // RNE f32 -> bf16
    unsigned int u = __float_as_uint(f);
    u += 0x7FFFu + ((u >> 16) & 1u);
    return (unsigned short)(u >> 16);
}
__device__ __forceinline__ float bf_lo(unsigned int u) { return __uint_as_float(u << 16); }
__device__ __forceinline__ float bf_hi(unsigned int u) { return __uint_as_float(u & 0xFFFF0000u); }

// ---------------------------------------------------------------- degree hist (cnt zeroed by memset)
__global__ void k_hist(const int* __restrict__ dst, int* cnt) {
    int e = blockIdx.x * 256 + threadIdx.x;
    if (e < N_EDGES) atomicAdd(&cnt[dst[e]], 1);
}

// ---------------------------------------------------------------- scan (exclusive over cnt; deg = cnt+1)
__global__ void k_scan1(const int* __restrict__ cnt, int* __restrict__ part) {
    __shared__ int s[256];
    int t = threadIdx.x;
    int i = blockIdx.x * 256 + t;
    int v = (i < N_NODES) ? cnt[i] : 0;
    s[t] = v; __syncthreads();
    for (int off = 128; off > 0; off >>= 1) {
        if (t < off) s[t] += s[t + off];
        __syncthreads();
    }
    if (t == 0) part[blockIdx.x] = s[0];
}

__global__ void k_scan2(int* __restrict__ part, int* __restrict__ row_ptr, int nb) {
    __shared__ int s[512];
    int t = threadIdx.x;
    int v = (t < nb) ? part[t] : 0;
    int orig = v;
    s[t] = v; __syncthreads();
    for (int off = 1; off < 512; off <<= 1) {
        int u = (t >= off) ? s[t - off] : 0;
        __syncthreads();
        s[t] += u;
        __syncthreads();
    }
    if (t < nb) part[t] = s[t] - orig;       // exclusive
    if (t == 0) row_ptr[N_NODES] = N_EDGES;
}

// scan3 also emits cursor and dis
__global__ void k_scan3(const int* __restrict__ cnt, const int* __restrict__ part,
                        int* __restrict__ row_ptr, int* __restrict__ cursor,
                        float* __restrict__ dis) {
    __shared__ int s[256];
    int t = threadIdx.x;
    int i = blockIdx.x * 256 + t;
    int v = (i < N_NODES) ? cnt[i] : 0;
    s[t] = v; __syncthreads();
    for (int off = 1; off < 256; off <<= 1) {
        int u = (t >= off) ? s[t - off] : 0;
        __syncthreads();
        s[t] += u;
        __syncthreads();
    }
    int ex = s[t] - v + part[blockIdx.x];
    if (i < N_NODES) {
        row_ptr[i] = ex; cursor[i] = ex;
        dis[i] = 1.0f / sqrtf((float)(v + 1));   // deg includes self-loop
    }
}

// ---------------------------------------------------------------- CSR scatter
__global__ void k_scatter(const int* __restrict__ src, const int* __restrict__ dst,
                          const float* __restrict__ dis, int* __restrict__ cursor,
                          int* __restrict__ csr_src, float* __restrict__ csr_norm) {
    int e = blockIdx.x * 256 + threadIdx.x;
    if (e >= N_EDGES) return;
    int s = src[e], d = dst[e];
    int pos = atomicAdd(&cursor[d], 1);
    csr_src[pos] = s;
    csr_norm[pos] = dis[s] * dis[d];
}

// ---------------------------------------------------------------- pack W2/W3 to B-frag order
__device__ __forceinline__ void pack_one(const float* __restrict__ W, unsigned short* __restrict__ out,
                                         int idx, int N) {
    int lane = idx & 63;
    int ks = (idx >> 6) & 3;
    int ct = idx >> 8;
    int n = ct * 16 + (lane & 15);
    int kbase = ks * 32 + (lane >> 4) * 8;
    #pragma unroll
    for (int j = 0; j < 8; ++j)
        out[(size_t)idx * 8 + j] = f2bf(W[(size_t)(kbase + j) * N + n]);
}

__global__ void k_pack_w_both(const float* __restrict__ W2, const float* __restrict__ W3,
                              unsigned short* __restrict__ Wp2, unsigned short* __restrict__ Wp3) {
    int idx = blockIdx.x * 256 + threadIdx.x;        // 12 blocks = 3072
    if (idx < 2048) pack_one(W2, Wp2, idx, 128);
    else if (idx < 3072) pack_one(W3, Wp3, idx - 2048, 64);
}

// ---------------------------------------------------------------- layer 1 fused: agg(F=3) + GEMM 3->128 + b1 + relu -> bf16
__global__ __launch_bounds__(256) void k_node1(const float* __restrict__ x,
                                               const float* __restrict__ dis,
                                               const int* __restrict__ row_ptr,
                                               const int* __restrict__ csr_src,
                                               const float* __restrict__ csr_norm,
                                               const float* __restrict__ W1,
                                               const float* __restrict__ b1,
                                               unsigned short* __restrict__ out) {
    __shared__ float Ws[384];
    __shared__ float bs[128];
    int tid = threadIdx.x;
    for (int i = tid; i < 384; i += 256) Ws[i] = W1[i];
    if (tid < 128) bs[tid] = b1[tid];
    __syncthreads();
    int wid = (blockIdx.x * 256 + tid) >> 6;
    int lane = tid & 63;
    if (wid >= N_NODES) return;
    int beg = row_ptr[wid], end = row_ptr[wid + 1];
    float p0 = 0.f, p1 = 0.f, p2 = 0.f;
    for (int e = beg + lane; e < end; e += 64) {
        int s = csr_src[e];
        float n = csr_norm[e];
        p0 = fmaf(x[s * 3 + 0], n, p0);
        p1 = fmaf(x[s * 3 + 1], n, p1);
        p2 = fmaf(x[s * 3 + 2], n, p2);
    }
    #pragma unroll
    for (int m = 32; m > 0; m >>= 1) {          // butterfly: all lanes get totals
        p0 += __shfl_xor(p0, m, 64);
        p1 += __shfl_xor(p1, m, 64);
        p2 += __shfl_xor(p2, m, 64);
    }
    float d = dis[wid], s2 = d * d;
    float a0 = fmaf(x[wid * 3 + 0], s2, p0);
    float a1 = fmaf(x[wid * 3 + 1], s2, p1);
    float a2 = fmaf(x[wid * 3 + 2], s2, p2);
    int f = 2 * lane;
    float v0 = bs[f]     + a0 * Ws[f]     + a1 * Ws[128 + f]     + a2 * Ws[256 + f];
    float v1 = bs[f + 1] + a0 * Ws[f + 1] + a1 * Ws[128 + f + 1] + a2 * Ws[256 + f + 1];
    unsigned int w = ((unsigned int)f2bf(fmaxf(v1, 0.f)) << 16) | (unsigned int)f2bf(fmaxf(v0, 0.f));
    *(unsigned int*)(out + (size_t)wid * 128 + f) = w;
}

// ---------------------------------------------------------------- layers 2+3 fused:
// agg(F=128 bf16, 2 nodes/wave concurrent) -> LDS -> MFMA GEMM2 (+b2, relu) -> LDS -> MFMA GEMM3 -> Q2b
// block = 32 nodes (100000 = 3125 * 32 exact). LDS rows padded to 136 ushorts.
__global__ __launch_bounds__(256) void k_layer23(const unsigned short* __restrict__ h1,
                                                 const float* __restrict__ dis,
                                                 const int* __restrict__ row_ptr,
                                                 const int* __restrict__ csr_src,
                                                 const float* __restrict__ csr_norm,
                                                 const unsigned short* __restrict__ Wp2,
                                                 const float* __restrict__ b2,
                                                 const unsigned short* __restrict__ Wp3,
                                                 unsigned short* __restrict__ Q2b) {
    __shared__ unsigned short Asb[32][136];   // aggregated h1 tile
    __shared__ unsigned short Hsb[32][136];   // h2 tile
    int tid = threadIdx.x;
    int wave = tid >> 6, lane = tid & 63;
    int quad = lane >> 4, m16 = lane & 15;
    int base = blockIdx.x * 32;

    // ---- phase 1: 2 nodes per wave concurrently; half-wave = 1 node, 4 feats/lane (8B gathers)
    int half = lane >> 5;          // 0/1: which node of the pair
    int l32 = lane & 31;           // feature quad: feats 4*l32 .. 4*l32+3
    for (int p = 0; p < 4; ++p) {
        int r = wave * 8 + p * 2 + half;
        int node = base + r;
        int beg = row_ptr[node], end = row_ptr[node + 1];
        float d = dis[node], s2 = d * d;
        uint2 su = *(const uint2*)(h1 + (size_t)node * 128 + 4 * l32);
        float a0 = bf_lo(su.x) * s2, a1 = bf_hi(su.x) * s2;
        float a2 = bf_lo(su.y) * s2, a3 = bf_hi(su.y) * s2;
        for (int e = beg; e < end; e += 8) {
            int idx[8]; float nn[8];
            #pragma unroll
            for (int u = 0; u < 8; ++u) {
                int ee = e + u;
                int cl = ee < end ? ee : end - 1;
                idx[u] = csr_src[cl];
                nn[u] = ee < end ? csr_norm[cl] : 0.0f;
            }
            uint2 uv[8];
            #pragma unroll
            for (int u = 0; u < 8; ++u)
                uv[u] = *(const uint2*)(h1 + (size_t)idx[u] * 128 + 4 * l32);
            #pragma unroll
            for (int u = 0; u < 8; ++u) {
                a0 = fmaf(bf_lo(uv[u].x), nn[u], a0);
                a1 = fmaf(bf_hi(uv[u].x), nn[u], a1);
                a2 = fmaf(bf_lo(uv[u].y), nn[u], a2);
                a3 = fmaf(bf_hi(uv[u].y), nn[u], a3);
            }
        }
        uint2 w;
        w.x = ((unsigned int)f2bf(a1) << 16) | (unsigned int)f2bf(a0);
        w.y = ((unsigned int)f2bf(a3) << 16) | (unsigned int)f2bf(a2);
        *(uint2*)(&Asb[r][4 * l32]) = w;
    }
    __syncthreads();

    // ---- phase 2: 32x128 = Asb(32x128) @ Wp2(128x128), +b2, relu -> Hsb
    int mt = wave & 1;                 // row tile (16 rows)
    int ch = wave >> 1;                // column half (64 cols)
    {
        short8 af[4];
        #pragma unroll
        for (int ks = 0; ks < 4; ++ks)
            af[ks] = *(const short8*)(&Asb[mt * 16 + m16][ks * 32 + quad * 8]);
        floatx4 acc[4];
        #pragma unroll
        for (int ct = 0; ct < 4; ++ct) acc[ct] = (floatx4){0.f, 0.f, 0.f, 0.f};
        #pragma unroll
        for (int ct = 0; ct < 4; ++ct) {
            int gct = ch * 4 + ct;
            #pragma unroll
            for (int ks = 0; ks < 4; ++ks) {
                short8 bf = *(const short8*)(Wp2 + ((size_t)(gct * 4 + ks) * 64 + lane) * 8);
                acc[ct] = __builtin_amdgcn_mfma_f32_16x16x32_bf16(af[ks], bf, acc[ct], 0, 0, 0);
            }
        }
        #pragma unroll
        for (int ct = 0; ct < 4; ++ct) {
            int col = (ch * 4 + ct) * 16 + m16;
            float bv = b2[col];
            #pragma unroll
            for (int r = 0; r < 4; ++r) {
                int row = mt * 16 + quad * 4 + r;
                Hsb[row][col] = f2bf(fmaxf(acc[ct][r] + bv, 0.0f));
            }
        }
    }
    __syncthreads();

    // ---- phase 3: 32x64 = Hsb(32x128) @ Wp3(128x64) -> global Q2b (bf16, no bias)
    {
        int cp = wave >> 1;            // column pair (32 cols)
        short8 hf[4];
        #pragma unroll
        for (int ks = 0; ks < 4; ++ks)
            hf[ks] = *(const short8*)(&Hsb[mt * 16 + m16][ks * 32 + quad * 8]);
        floatx4 acc3[2];
        acc3[0] = (floatx4){0.f, 0.f, 0.f, 0.f};
        acc3[1] = (floatx4){0.f, 0.f, 0.f, 0.f};
        #pragma unroll
        for (int ct = 0; ct < 2; ++ct) {
            int gct = cp * 2 + ct;
            #pragma unroll
            for (int ks = 0; ks < 4; ++ks) {
                short8 bf = *(const short8*)(Wp3 + ((size_t)(gct * 4 + ks) * 64 + lane) * 8);
                acc3[ct] = __builtin_amdgcn_mfma_f32_16x16x32_bf16(hf[ks], bf, acc3[ct], 0, 0, 0);
            }
        }
        #pragma unroll
        for (int ct = 0; ct < 2; ++ct) {
            int col = (cp * 2 + ct) * 16 + m16;
            #pragma unroll
            for (int r = 0; r < 4; ++r) {
                long row = base + mt * 16 + quad * 4 + r;
                Q2b[row * 64 + col] = f2bf(acc3[ct][r]);
            }
        }
    }
}

// ---------------------------------------------------------------- aggregation F=64 bf16 + bias + relu + Wl dot
// 4 nodes per wave concurrently: 16 lanes x 4 feats (8B gathers). 100000 = 4*25000 exact.
__global__ __launch_bounds__(256) void k_agg64_dot(const unsigned short* __restrict__ h,
                                                   const float* __restrict__ dis,
                                                   const int* __restrict__ row_ptr,
                                                   const int* __restrict__ csr_src,
                                                   const float* __restrict__ csr_norm,
                                                   const float* __restrict__ bias,
                                                   const float* __restrict__ Wl,
                                                   float* __restrict__ s_out) {
    int gw = (blockIdx.x * 256 + threadIdx.x) >> 6;  // wave id, 25000 total
    int lane = threadIdx.x & 63;
    int sub = lane >> 4, l16 = lane & 15;
    int node = gw * 4 + sub;
    if (node >= N_NODES) return;
    int beg = row_ptr[node], end = row_ptr[node + 1];
    float d = dis[node], s2 = d * d;
    uint2 su = *(const uint2*)(h + (size_t)node * 64 + 4 * l16);
    float a0 = bf_lo(su.x) * s2, a1 = bf_hi(su.x) * s2;
    float a2 = bf_lo(su.y) * s2, a3 = bf_hi(su.y) * s2;
    for (int e = beg; e < end; e += 8) {
        int idx[8]; float nn[8];
        #pragma unroll
        for (int u = 0; u < 8; ++u) {
            int ee = e + u;
            int cl = ee < end ? ee : end - 1;
            idx[u] = csr_src[cl];
            nn[u] = ee < end ? csr_norm[cl] : 0.0f;
        }
        uint2 uv[8];
        #pragma unroll
        for (int u = 0; u < 8; ++u)
            uv[u] = *(const uint2*)(h + (size_t)idx[u] * 64 + 4 * l16);
        #pragma unroll
        for (int u = 0; u < 8; ++u) {
            a0 = fmaf(bf_lo(uv[u].x), nn[u], a0);
            a1 = fmaf(bf_hi(uv[u].x), nn[u], a1);
            a2 = fmaf(bf_lo(uv[u].y), nn[u], a2);
            a3 = fmaf(bf_hi(uv[u].y), nn[u], a3);
        }
    }
    int f = 4 * l16;
    float v = fmaxf(a0 + bias[f + 0], 0.f) * Wl[f + 0]
            + fmaxf(a1 + bias[f + 1], 0.f) * Wl[f + 1]
            + fmaxf(a2 + bias[f + 2], 0.f) * Wl[f + 2]
            + fmaxf(a3 + bias[f + 3], 0.f) * Wl[f + 3];
    #pragma unroll
    for (int m = 8; m > 0; m >>= 1) v += __shfl_xor(v, m, 64);   // reduce within 16-lane group
    if (l16 == 0) s_out[node] = v;
}

// ---------------------------------------------------------------- pool over per-node scalars
__global__ __launch_bounds__(256) void k_pool2(const float* __restrict__ s,
                                               const int* __restrict__ batch,
                                               const float* __restrict__ bl,
                                               float* __restrict__ out) {
    int g = blockIdx.x;
    int tid = threadIdx.x;
    int lo = 0, hi = N_NODES;
    while (lo < hi) { int m = (lo + hi) >> 1; if (batch[m] < g) lo = m + 1; else hi = m; }
    int lo2 = lo, hi2 = N_NODES;
    while (lo2 < hi2) { int m = (lo2 + hi2) >> 1; if (batch[m] < g + 1) lo2 = m + 1; else hi2 = m; }
    float acc = 0.0f;
    for (int n = lo + tid; n < lo2; n += 256) acc += s[n];
    __shared__ float sm[256];
    sm[tid] = acc; __syncthreads();
    for (int off = 128; off > 0; off >>= 1) {
        if (tid < off) sm[tid] += sm[tid + off];
        __syncthreads();
    }
    if (tid == 0) out[g] = sm[0] / fmaxf((float)(lo2 - lo), 1.0f) + bl[0];
}

// ---------------------------------------------------------------- launcher
extern "C" void kernel_launch(void* const* d_in, const int* in_sizes, int n_in,
                              void* d_out, int out_size, void* d_ws, size_t ws_size,
                              hipStream_t stream) {
    const float* x     = (const float*)d_in[0];
    const int*   ei    = (const int*)d_in[1];     // [0..E) = src, [E..2E) = dst
    const int*   batch = (const int*)d_in[2];
    const float* W1 = (const float*)d_in[3];
    const float* b1 = (const float*)d_in[4];
    const float* W2 = (const float*)d_in[5];
    const float* b2 = (const float*)d_in[6];
    const float* W3 = (const float*)d_in[7];
    const float* b3 = (const float*)d_in[8];
    const float* Wl = (const float*)d_in[9];
    const float* bl = (const float*)d_in[10];
    float* out = (float*)d_out;

    const int* e_src = ei;
    const int* e_dst = ei + N_EDGES;

    char* ws = (char*)d_ws;
    size_t off = 0;
    auto alloc = [&](size_t bytes) -> char* {
        char* p = ws + off;
        off = (off + bytes + 255) & ~(size_t)255;
        return p;
    };
    int*   cnt      = (int*)  alloc((size_t)N_NODES * 4);
    float* dis      = (float*)alloc((size_t)N_NODES * 4);
    int*   row_ptr  = (int*)  alloc((size_t)(N_NODES + 1) * 4);
    int*   cursor   = (int*)  alloc((size_t)N_NODES * 4);
    int*   part     = (int*)  alloc(1024 * 4);
    int*   csr_src  = (int*)  alloc((size_t)N_EDGES * 4);
    float* csr_norm = (float*)alloc((size_t)N_EDGES * 4);
    float* nscal    = (float*)alloc((size_t)N_NODES * 4);
    unsigned short* P1b = (unsigned short*)alloc((size_t)N_NODES * 128 * 2); // h1 bf16
    unsigned short* Q2b = (unsigned short*)alloc((size_t)N_NODES * 64 * 2);  // h2@W3 bf16
    unsigned short* Wp2 = (unsigned short*)alloc((size_t)128 * 128 * 2);
    unsigned short* Wp3 = (unsigned short*)alloc((size_t)128 * 64 * 2);

    const int NB_N = (N_NODES + 255) / 256;   // 391
    const int NB_E = (N_EDGES + 255) / 256;

    hipMemsetAsync(cnt, 0, (size_t)N_NODES * 4, stream);
    k_hist<<<NB_E, 256, 0, stream>>>(e_dst, cnt);
    k_scan1<<<NB_N, 256, 0, stream>>>(cnt, part);
    k_scan2<<<1, 512, 0, stream>>>(part, row_ptr, NB_N);
    k_scan3<<<NB_N, 256, 0, stream>>>(cnt, part, row_ptr, cursor, dis);
    k_scatter<<<NB_E, 256, 0, stream>>>(e_src, e_dst, dis, cursor, csr_src, csr_norm);
    k_pack_w_both<<<12, 256, 0, stream>>>(W2, W3, Wp2, Wp3);

    // layer 1 fused: agg(F=3) + GEMM 3->128 + b1 + relu -> bf16
    k_node1<<<(N_NODES * 64 + 255) / 256, 256, 0, stream>>>(x, dis, row_ptr, csr_src, csr_norm,
                                                            W1, b1, P1b);

    // layers 2+3 fused: agg(F=128) + GEMM2(+b2,relu) + GEMM3 -> Q2b bf16
    k_layer23<<<N_NODES / 32, 256, 0, stream>>>(P1b, dis, row_ptr, csr_src, csr_norm,
                                                Wp2, b2, Wp3, Q2b);

    // layer 3 aggregation + b3 + relu + dot(Wl)  (4 nodes/wave -> 6250 blocks)
    k_agg64_dot<<<N_NODES / 4 / 4, 256, 0, stream>>>(Q2b, dis, row_ptr, csr_src, csr_norm,
                                                     b3, Wl, nscal);

    // mean pool (+ bl) over per-node scalars
    k_pool2<<<N_GRAPHS, 256, 0, stream>>>(nscal, batch, bl, out);
}

// Round 8
// 221.189 us; speedup vs baseline: 2.1743x; 1.1598x over previous
//
#include <hip/hip_runtime.h>

#define N_NODES 100000
#define N_EDGES 600000
#define N_GRAPHS 512

typedef __attribute__((ext_vector_type(8))) short short8;
typedef __attribute__((ext_vector_type(4))) float floatx4;

__device__ __forceinline__ unsigned short f2bf(float f) {   // RNE f32 -> bf16
    unsigned int u = __float_as_uint(f);
    u += 0x7FFFu + ((u >> 16) & 1u);
    return (unsigned short)(u >> 16);
}
__device__ __forceinline__ float bf_lo(unsigned int u) { return __uint_as_float(u << 16); }
__device__ __forceinline__ float bf_hi(unsigned int u) { return __uint_as_float(u & 0xFFFF0000u); }

__device__ __forceinline__ void fma8(float* a, short8 v, float n) {
    union { short8 s; unsigned int u[4]; } c; c.s = v;
    #pragma unroll
    for (int j = 0; j < 4; ++j) {
        a[2 * j]     = fmaf(bf_lo(c.u[j]), n, a[2 * j]);
        a[2 * j + 1] = fmaf(bf_hi(c.u[j]), n, a[2 * j + 1]);
    }
}
__device__ __forceinline__ void init8(float* a, short8 v, float s) {
    union { short8 s; unsigned int u[4]; } c; c.s = v;
    #pragma unroll
    for (int j = 0; j < 4; ++j) {
        a[2 * j]     = bf_lo(c.u[j]) * s;
        a[2 * j + 1] = bf_hi(c.u[j]) * s;
    }
}
__device__ __forceinline__ short8 pack8(const float* a) {
    short8 r;
    #pragma unroll
    for (int j = 0; j < 8; ++j) r[j] = (short)f2bf(a[j]);
    return r;
}

// ---------------------------------------------------------------- degree hist (cnt zeroed by memset)
__global__ void k_hist(const int* __restrict__ dst, int* cnt) {
    int e = blockIdx.x * 256 + threadIdx.x;
    if (e < N_EDGES) atomicAdd(&cnt[dst[e]], 1);
}

// ---------------------------------------------------------------- scan (exclusive over cnt; deg = cnt+1)
__global__ void k_scan1(const int* __restrict__ cnt, int* __restrict__ part) {
    __shared__ int s[256];
    int t = threadIdx.x;
    int i = blockIdx.x * 256 + t;
    int v = (i < N_NODES) ? cnt[i] : 0;
    s[t] = v; __syncthreads();
    for (int off = 128; off > 0; off >>= 1) {
        if (t < off) s[t] += s[t + off];
        __syncthreads();
    }
    if (t == 0) part[blockIdx.x] = s[0];
}

__global__ void k_scan2(int* __restrict__ part, int* __restrict__ row_ptr, int nb) {
    __shared__ int s[512];
    int t = threadIdx.x;
    int v = (t < nb) ? part[t] : 0;
    int orig = v;
    s[t] = v; __syncthreads();
    for (int off = 1; off < 512; off <<= 1) {
        int u = (t >= off) ? s[t - off] : 0;
        __syncthreads();
        s[t] += u;
        __syncthreads();
    }
    if (t < nb) part[t] = s[t] - orig;       // exclusive
    if (t == 0) row_ptr[N_NODES] = N_EDGES;
}

// scan3 also emits cursor and dis
__global__ void k_scan3(const int* __restrict__ cnt, const int* __restrict__ part,
                        int* __restrict__ row_ptr, int* __restrict__ cursor,
                        float* __restrict__ dis) {
    __shared__ int s[256];
    int t = threadIdx.x;
    int i = blockIdx.x * 256 + t;
    int v = (i < N_NODES) ? cnt[i] : 0;
    s[t] = v; __syncthreads();
    for (int off = 1; off < 256; off <<= 1) {
        int u = (t >= off) ? s[t - off] : 0;
        __syncthreads();
        s[t] += u;
        __syncthreads();
    }
    int ex = s[t] - v + part[blockIdx.x];
    if (i < N_NODES) {
        row_ptr[i] = ex; cursor[i] = ex;
        dis[i] = 1.0f / sqrtf((float)(v + 1));   // deg includes self-loop
    }
}

// ---------------------------------------------------------------- CSR scatter
__global__ void k_scatter(const int* __restrict__ src, const int* __restrict__ dst,
                          const float* __restrict__ dis, int* __restrict__ cursor,
                          int* __restrict__ csr_src, float* __restrict__ csr_norm) {
    int e = blockIdx.x * 256 + threadIdx.x;
    if (e >= N_EDGES) return;
    int s = src[e], d = dst[e];
    int pos = atomicAdd(&cursor[d], 1);
    csr_src[pos] = s;
    csr_norm[pos] = dis[s] * dis[d];
}

// ---------------------------------------------------------------- pack W2/W3 to B-frag order
__device__ __forceinline__ void pack_one(const float* __restrict__ W, unsigned short* __restrict__ out,
                                         int idx, int N) {
    int lane = idx & 63;
    int ks = (idx >> 6) & 3;
    int ct = idx >> 8;
    int n = ct * 16 + (lane & 15);
    int kbase = ks * 32 + (lane >> 4) * 8;
    #pragma unroll
    for (int j = 0; j < 8; ++j)
        out[(size_t)idx * 8 + j] = f2bf(W[(size_t)(kbase + j) * N + n]);
}

__global__ void k_pack_w_both(const float* __restrict__ W2, const float* __restrict__ W3,
                              unsigned short* __restrict__ Wp2, unsigned short* __restrict__ Wp3) {
    int idx = blockIdx.x * 256 + threadIdx.x;        // 12 blocks = 3072
    if (idx < 2048) pack_one(W2, Wp2, idx, 128);
    else if (idx < 3072) pack_one(W3, Wp3, idx - 2048, 64);
}

// ---------------------------------------------------------------- layer 1 fused: agg(F=3) + GEMM 3->128 + b1 + relu -> bf16
// 4 nodes/wave: 16 lanes per node gather edges, butterfly(16), then 8 outputs/lane.
__global__ __launch_bounds__(256) void k_node1(const float* __restrict__ x,
                                               const float* __restrict__ dis,
                                               const int* __restrict__ row_ptr,
                                               const int* __restrict__ csr_src,
                                               const float* __restrict__ csr_norm,
                                               const float* __restrict__ W1,
                                               const float* __restrict__ b1,
                                               unsigned short* __restrict__ out) {
    __shared__ float Ws[384];
    __shared__ float bs[128];
    int tid = threadIdx.x;
    for (int i = tid; i < 384; i += 256) Ws[i] = W1[i];
    if (tid < 128) bs[tid] = b1[tid];
    __syncthreads();
    int gw = (blockIdx.x * 256 + tid) >> 6;          // 25000 waves
    int lane = tid & 63;
    int sub = lane >> 4, l16 = lane & 15;
    int node = gw * 4 + sub;                         // 100000 = 25000*4 exact
    int beg = row_ptr[node], end = row_ptr[node + 1];
    float p0 = 0.f, p1 = 0.f, p2 = 0.f;
    for (int e = beg + l16; e < end; e += 16) {
        int s = csr_src[e];
        float n = csr_norm[e];
        p0 = fmaf(x[s * 3 + 0], n, p0);
        p1 = fmaf(x[s * 3 + 1], n, p1);
        p2 = fmaf(x[s * 3 + 2], n, p2);
    }
    #pragma unroll
    for (int m = 8; m > 0; m >>= 1) {                // butterfly within 16-lane group
        p0 += __shfl_xor(p0, m, 64);
        p1 += __shfl_xor(p1, m, 64);
        p2 += __shfl_xor(p2, m, 64);
    }
    float d = dis[node], s2 = d * d;
    float a0 = fmaf(x[node * 3 + 0], s2, p0);
    float a1 = fmaf(x[node * 3 + 1], s2, p1);
    float a2 = fmaf(x[node * 3 + 2], s2, p2);
    int f = l16 * 8;
    float v[8];
    #pragma unroll
    for (int j = 0; j < 8; ++j)
        v[j] = fmaxf(bs[f + j] + a0 * Ws[f + j] + a1 * Ws[128 + f + j] + a2 * Ws[256 + f + j], 0.f);
    *(short8*)(out + (size_t)node * 128 + f) = pack8(v);
}

// ---------------------------------------------------------------- layers 2+3 fused:
// agg(F=128 bf16): 16 lanes/node, 16B short8 gathers, idx for both node-groups prefetched.
// -> LDS -> MFMA GEMM2 (+b2, relu) -> LDS -> MFMA GEMM3 -> Q2b
// block = 32 nodes (100000 = 3125 * 32 exact). LDS rows padded to 136 ushorts.
__global__ __launch_bounds__(256) void k_layer23(const unsigned short* __restrict__ h1,
                                                 const float* __restrict__ dis,
                                                 const int* __restrict__ row_ptr,
                                                 const int* __restrict__ csr_src,
                                                 const float* __restrict__ csr_norm,
                                                 const unsigned short* __restrict__ Wp2,
                                                 const float* __restrict__ b2,
                                                 const unsigned short* __restrict__ Wp3,
                                                 unsigned short* __restrict__ Q2b) {
    __shared__ unsigned short Asb[32][136];   // aggregated h1 tile
    __shared__ unsigned short Hsb[32][136];   // h2 tile
    int tid = threadIdx.x;
    int wave = tid >> 6, lane = tid & 63;
    int quad = lane >> 4, m16 = lane & 15;
    int base = blockIdx.x * 32;

    // ---- phase 1: 8 nodes per wave in 2 groups of 4; 16 lanes/node, 8 feats/lane.
    {
        int sub = lane >> 4, l16 = lane & 15;
        int rA = wave * 8 + sub, rB = rA + 4;
        int nodeA = base + rA, nodeB = base + rB;
        int begA = row_ptr[nodeA], endA = row_ptr[nodeA + 1];
        int begB = row_ptr[nodeB], endB = row_ptr[nodeB + 1];
        // prefetch idx/norm for both groups (independent -> one latency round)
        int idxA[8], idxB[8]; float nnA[8], nnB[8];
        #pragma unroll
        for (int u = 0; u < 8; ++u) {
            int ee = begA + u; int cl = ee < endA ? ee : endA - 1;
            idxA[u] = csr_src[cl]; nnA[u] = ee < endA ? csr_norm[cl] : 0.0f;
        }
        #pragma unroll
        for (int u = 0; u < 8; ++u) {
            int ee = begB + u; int cl = ee < endB ? ee : endB - 1;
            idxB[u] = csr_src[cl]; nnB[u] = ee < endB ? csr_norm[cl] : 0.0f;
        }
        float dA = dis[nodeA], dB = dis[nodeB];
        short8 selfA = *(const short8*)(h1 + (size_t)nodeA * 128 + l16 * 8);
        short8 selfB = *(const short8*)(h1 + (size_t)nodeB * 128 + l16 * 8);

        // group A: 8 gathers of 16B in flight
        short8 gA[8];
        #pragma unroll
        for (int u = 0; u < 8; ++u)
            gA[u] = *(const short8*)(h1 + (size_t)idxA[u] * 128 + l16 * 8);
        float aA[8];
        init8(aA, selfA, dA * dA);
        #pragma unroll
        for (int u = 0; u < 8; ++u) fma8(aA, gA[u], nnA[u]);
        for (int e = begA + 8; e < endA; e += 8) {       // rare remainder
            int idx[8]; float nn[8];
            #pragma unroll
            for (int u = 0; u < 8; ++u) {
                int ee = e + u; int cl = ee < endA ? ee : endA - 1;
                idx[u] = csr_src[cl]; nn[u] = ee < endA ? csr_norm[cl] : 0.0f;
            }
            short8 g[8];
            #pragma unroll
            for (int u = 0; u < 8; ++u)
                g[u] = *(const short8*)(h1 + (size_t)idx[u] * 128 + l16 * 8);
            #pragma unroll
            for (int u = 0; u < 8; ++u) fma8(aA, g[u], nn[u]);
        }
        *(short8*)(&Asb[rA][l16 * 8]) = pack8(aA);

        // group B
        short8 gB[8];
        #pragma unroll
        for (int u = 0; u < 8; ++u)
            gB[u] = *(const short8*)(h1 + (size_t)idxB[u] * 128 + l16 * 8);
        float aB[8];
        init8(aB, selfB, dB * dB);
        #pragma unroll
        for (int u = 0; u < 8; ++u) fma8(aB, gB[u], nnB[u]);
        for (int e = begB + 8; e < endB; e += 8) {       // rare remainder
            int idx[8]; float nn[8];
            #pragma unroll
            for (int u = 0; u < 8; ++u) {
                int ee = e + u; int cl = ee < endB ? ee : endB - 1;
                idx[u] = csr_src[cl]; nn[u] = ee < endB ? csr_norm[cl] : 0.0f;
            }
            short8 g[8];
            #pragma unroll
            for (int u = 0; u < 8; ++u)
                g[u] = *(const short8*)(h1 + (size_t)idx[u] * 128 + l16 * 8);
            #pragma unroll
            for (int u = 0; u < 8; ++u) fma8(aB, g[u], nn[u]);
        }
        *(short8*)(&Asb[rB][l16 * 8]) = pack8(aB);
    }
    __syncthreads();

    // ---- phase 2: 32x128 = Asb(32x128) @ Wp2(128x128), +b2, relu -> Hsb
    int mt = wave & 1;                 // row tile (16 rows)
    int ch = wave >> 1;                // column half (64 cols)
    {
        short8 af[4];
        #pragma unroll
        for (int ks = 0; ks < 4; ++ks)
            af[ks] = *(const short8*)(&Asb[mt * 16 + m16][ks * 32 + quad * 8]);
        floatx4 acc[4];
        #pragma unroll
        for (int ct = 0; ct < 4; ++ct) acc[ct] = (floatx4){0.f, 0.f, 0.f, 0.f};
        #pragma unroll
        for (int ct = 0; ct < 4; ++ct) {
            int gct = ch * 4 + ct;
            #pragma unroll
            for (int ks = 0; ks < 4; ++ks) {
                short8 bf = *(const short8*)(Wp2 + ((size_t)(gct * 4 + ks) * 64 + lane) * 8);
                acc[ct] = __builtin_amdgcn_mfma_f32_16x16x32_bf16(af[ks], bf, acc[ct], 0, 0, 0);
            }
        }
        #pragma unroll
        for (int ct = 0; ct < 4; ++ct) {
            int col = (ch * 4 + ct) * 16 + m16;
            float bv = b2[col];
            #pragma unroll
            for (int r = 0; r < 4; ++r) {
                int row = mt * 16 + quad * 4 + r;
                Hsb[row][col] = f2bf(fmaxf(acc[ct][r] + bv, 0.0f));
            }
        }
    }
    __syncthreads();

    // ---- phase 3: 32x64 = Hsb(32x128) @ Wp3(128x64) -> global Q2b (bf16, no bias)
    {
        int cp = wave >> 1;            // column pair (32 cols)
        short8 hf[4];
        #pragma unroll
        for (int ks = 0; ks < 4; ++ks)
            hf[ks] = *(const short8*)(&Hsb[mt * 16 + m16][ks * 32 + quad * 8]);
        floatx4 acc3[2];
        acc3[0] = (floatx4){0.f, 0.f, 0.f, 0.f};
        acc3[1] = (floatx4){0.f, 0.f, 0.f, 0.f};
        #pragma unroll
        for (int ct = 0; ct < 2; ++ct) {
            int gct = cp * 2 + ct;
            #pragma unroll
            for (int ks = 0; ks < 4; ++ks) {
                short8 bf = *(const short8*)(Wp3 + ((size_t)(gct * 4 + ks) * 64 + lane) * 8);
                acc3[ct] = __builtin_amdgcn_mfma_f32_16x16x32_bf16(hf[ks], bf, acc3[ct], 0, 0, 0);
            }
        }
        #pragma unroll
        for (int ct = 0; ct < 2; ++ct) {
            int col = (cp * 2 + ct) * 16 + m16;
            #pragma unroll
            for (int r = 0; r < 4; ++r) {
                long row = base + mt * 16 + quad * 4 + r;
                Q2b[row * 64 + col] = f2bf(acc3[ct][r]);
            }
        }
    }
}

// ---------------------------------------------------------------- aggregation F=64 bf16 + bias + relu + Wl dot
// 8 nodes/wave: 8 lanes x 8 feats (16B short8 gathers), single gather round.
__global__ __launch_bounds__(256) void k_agg64_dot(const unsigned short* __restrict__ h,
                                                   const float* __restrict__ dis,
                                                   const int* __restrict__ row_ptr,
                                                   const int* __restrict__ csr_src,
                                                   const float* __restrict__ csr_norm,
                                                   const float* __restrict__ bias,
                                                   const float* __restrict__ Wl,
                                                   float* __restrict__ s_out) {
    int gw = (blockIdx.x * 256 + threadIdx.x) >> 6;  // 12500 waves
    int lane = threadIdx.x & 63;
    int sub = lane >> 3, l8 = lane & 7;
    int node = gw * 8 + sub;                         // 100000 = 12500*8 exact
    int beg = row_ptr[node], end = row_ptr[node + 1];
    int idx[8]; float nn[8];
    #pragma unroll
    for (int u = 0; u < 8; ++u) {
        int ee = beg + u; int cl = ee < end ? ee : end - 1;
        idx[u] = csr_src[cl]; nn[u] = ee < end ? csr_norm[cl] : 0.0f;
    }
    float d = dis[node];
    short8 self = *(const short8*)(h + (size_t)node * 64 + l8 * 8);
    short8 g[8];
    #pragma unroll
    for (int u = 0; u < 8; ++u)
        g[u] = *(const short8*)(h + (size_t)idx[u] * 64 + l8 * 8);
    float a[8];
    init8(a, self, d * d);
    #pragma unroll
    for (int u = 0; u < 8; ++u) fma8(a, g[u], nn[u]);
    for (int e = beg + 8; e < end; e += 8) {         // rare remainder
        int idx2[8]; float nn2[8];
        #pragma unroll
        for (int u = 0; u < 8; ++u) {
            int ee = e + u; int cl = ee < end ? ee : end - 1;
            idx2[u] = csr_src[cl]; nn2[u] = ee < end ? csr_norm[cl] : 0.0f;
        }
        short8 g2[8];
        #pragma unroll
        for (int u = 0; u < 8; ++u)
            g2[u] = *(const short8*)(h + (size_t)idx2[u] * 64 + l8 * 8);
        #pragma unroll
        for (int u = 0; u < 8; ++u) fma8(a, g2[u], nn2[u]);
    }
    int f = l8 * 8;
    float v = 0.f;
    #pragma unroll
    for (int j = 0; j < 8; ++j)
        v = fmaf(fmaxf(a[j] + bias[f + j], 0.f), Wl[f + j], v);
    #pragma unroll
    for (int m = 4; m > 0; m >>= 1) v += __shfl_xor(v, m, 64);   // reduce within 8-lane group
    if (l8 == 0) s_out[node] = v;
}

// ---------------------------------------------------------------- pool over per-node scalars
__global__ __launch_bounds__(256) void k_pool2(const float* __restrict__ s,
                                               const int* __restrict__ batch,
                                               const float* __restrict__ bl,
                                               float* __restrict__ out) {
    int g = blockIdx.x;
    int tid = threadIdx.x;
    int lo = 0, hi = N_NODES;
    while (lo < hi) { int m = (lo + hi) >> 1; if (batch[m] < g) lo = m + 1; else hi = m; }
    int lo2 = lo, hi2 = N_NODES;
    while (lo2 < hi2) { int m = (lo2 + hi2) >> 1; if (batch[m] < g + 1) lo2 = m + 1; else hi2 = m; }
    float acc = 0.0f;
    for (int n = lo + tid; n < lo2; n += 256) acc += s[n];
    __shared__ float sm[256];
    sm[tid] = acc; __syncthreads();
    for (int off = 128; off > 0; off >>= 1) {
        if (tid < off) sm[tid] += sm[tid + off];
        __syncthreads();
    }
    if (tid == 0) out[g] = sm[0] / fmaxf((float)(lo2 - lo), 1.0f) + bl[0];
}

// ---------------------------------------------------------------- launcher
extern "C" void kernel_launch(void* const* d_in, const int* in_sizes, int n_in,
                              void* d_out, int out_size, void* d_ws, size_t ws_size,
                              hipStream_t stream) {
    const float* x     = (const float*)d_in[0];
    const int*   ei    = (const int*)d_in[1];     // [0..E) = src, [E..2E) = dst
    const int*   batch = (const int*)d_in[2];
    const float* W1 = (const float*)d_in[3];
    const float* b1 = (const float*)d_in[4];
    const float* W2 = (const float*)d_in[5];
    const float* b2 = (const float*)d_in[6];
    const float* W3 = (const float*)d_in[7];
    const float* b3 = (const float*)d_in[8];
    const float* Wl = (const float*)d_in[9];
    const float* bl = (const float*)d_in[10];
    float* out = (float*)d_out;

    const int* e_src = ei;
    const int* e_dst = ei + N_EDGES;

    char* ws = (char*)d_ws;
    size_t off = 0;
    auto alloc = [&](size_t bytes) -> char* {
        char* p = ws + off;
        off = (off + bytes + 255) & ~(size_t)255;
        return p;
    };
    int*   cnt      = (int*)  alloc((size_t)N_NODES * 4);
    float* dis      = (float*)alloc((size_t)N_NODES * 4);
    int*   row_ptr  = (int*)  alloc((size_t)(N_NODES + 1) * 4);
    int*   cursor   = (int*)  alloc((size_t)N_NODES * 4);
    int*   part     = (int*)  alloc(1024 * 4);
    int*   csr_src  = (int*)  alloc((size_t)N_EDGES * 4);
    float* csr_norm = (float*)alloc((size_t)N_EDGES * 4);
    float* nscal    = (float*)alloc((size_t)N_NODES * 4);
    unsigned short* P1b = (unsigned short*)alloc((size_t)N_NODES * 128 * 2); // h1 bf16
    unsigned short* Q2b = (unsigned short*)alloc((size_t)N_NODES * 64 * 2);  // h2@W3 bf16
    unsigned short* Wp2 = (unsigned short*)alloc((size_t)128 * 128 * 2);
    unsigned short* Wp3 = (unsigned short*)alloc((size_t)128 * 64 * 2);

    const int NB_N = (N_NODES + 255) / 256;   // 391
    const int NB_E = (N_EDGES + 255) / 256;

    hipMemsetAsync(cnt, 0, (size_t)N_NODES * 4, stream);
    k_hist<<<NB_E, 256, 0, stream>>>(e_dst, cnt);
    k_scan1<<<NB_N, 256, 0, stream>>>(cnt, part);
    k_scan2<<<1, 512, 0, stream>>>(part, row_ptr, NB_N);
    k_scan3<<<NB_N, 256, 0, stream>>>(cnt, part, row_ptr, cursor, dis);
    k_scatter<<<NB_E, 256, 0, stream>>>(e_src, e_dst, dis, cursor, csr_src, csr_norm);
    k_pack_w_both<<<12, 256, 0, stream>>>(W2, W3, Wp2, Wp3);

    // layer 1 fused: agg(F=3) + GEMM 3->128 + b1 + relu -> bf16  (4 nodes/wave)
    k_node1<<<N_NODES / 4 / 4, 256, 0, stream>>>(x, dis, row_ptr, csr_src, csr_norm,
                                                 W1, b1, P1b);

    // layers 2+3 fused: agg(F=128) + GEMM2(+b2,relu) + GEMM3 -> Q2b bf16
    k_layer23<<<N_NODES / 32, 256, 0, stream>>>(P1b, dis, row_ptr, csr_src, csr_norm,
                                                Wp2, b2, Wp3, Q2b);

    // layer 3 aggregation + b3 + relu + dot(Wl)  (8 nodes/wave -> 3125 blocks)
    k_agg64_dot<<<N_NODES / 8 / 4, 256, 0, stream>>>(Q2b, dis, row_ptr, csr_src, csr_norm,
                                                     b3, Wl, nscal);

    // mean pool (+ bl) over per-node scalars
    k_pool2<<<N_GRAPHS, 256, 0, stream>>>(nscal, batch, bl, out);
}